// Round 1
// baseline (559.299 us; speedup 1.0000x reference)
//
#include <hip/hip_runtime.h>
#include <hip/hip_bf16.h>
#include <cstdint>
#include <cstddef>

typedef __attribute__((ext_vector_type(8))) short short8;
typedef __attribute__((ext_vector_type(4))) float f32x4;

#define AS1U32(p) ((const __attribute__((address_space(1))) uint32_t*)(p))
#define AS3U32(p) ((__attribute__((address_space(3))) uint32_t*)(p))

__device__ __forceinline__ unsigned short f2bf(float v) {
  union { float f; uint32_t u; } a; a.f = v;
  uint32_t u = a.u;
  u += 0x7FFFu + ((u >> 16) & 1u);   // round-to-nearest-even
  return (unsigned short)(u >> 16);
}

// gelu(x) = x * sigmoid(2u), u = sqrt(2/pi)(x + 0.044715 x^3)
__device__ __forceinline__ float gelu_fast(float x) {
  const float c0 = 0.7978845608028654f;
  const float c1 = 0.044715f;
  float u = c0 * (x + c1 * x * x * x);
  return x * __builtin_amdgcn_rcpf(1.0f + __expf(-2.0f * u));
}

// ---------------- prologue kernels (unchanged) ----------------

__global__ __launch_bounds__(512)
void reduce_part(const float* __restrict__ x, float* __restrict__ kpart) {
  const int d = threadIdx.x;
  const int b = blockIdx.x;
  float s = 0.f;
#pragma unroll 4
  for (int i = 0; i < 64; i++)
    s += x[((size_t)b * 64 + i) * 512 + d];
  kpart[(size_t)b * 512 + d] = s;
}

__global__ __launch_bounds__(1024)
void gate_all(const float* __restrict__ kpart,
              const float* __restrict__ gate_w,
              const float* __restrict__ gate_b,
              const float* __restrict__ b1, const float* __restrict__ b2,
              int* __restrict__ idxout,
              float* __restrict__ b1cat, float* __restrict__ b2sel) {
  __shared__ float ksum2[2][512];
  __shared__ float coarse[16];
  __shared__ int idxl[4];
  const int t = threadIdx.x;
  {
    const int d = t & 511, h = t >> 9;
    float s = 0.f;
    for (int p = h * 128; p < h * 128 + 128; p++) s += kpart[(size_t)p * 512 + d];
    ksum2[h][d] = s;
  }
  __syncthreads();
  {
    const int wave = t >> 6, lane = t & 63;
    const int d0 = lane * 8;
    float s = 0.f;
#pragma unroll
    for (int j = 0; j < 8; j++)
      s += gate_w[wave * 512 + d0 + j] * (ksum2[0][d0 + j] + ksum2[1][d0 + j]);
#pragma unroll
    for (int off = 32; off >= 1; off >>= 1) s += __shfl_down(s, off, 64);
    if (lane == 0) coarse[wave] = s + gate_b[wave];
  }
  __syncthreads();
  if (t == 0) {
    unsigned taken = 0;
    for (int r = 0; r < 4; r++) {
      float best = -3.4e38f; int bi = 0;
      for (int e = 0; e < 16; e++)
        if (!((taken >> e) & 1u) && coarse[e] > best) { best = coarse[e]; bi = e; }
      taken |= 1u << bi;
      idxl[r] = bi; idxout[r] = bi;
    }
  }
  __syncthreads();
  for (int i = t; i < 8192; i += 1024)
    b1cat[i] = b1[(size_t)idxl[i >> 11] * 2048 + (i & 2047)];
  for (int i = t; i < 2048; i += 1024)
    b2sel[i] = b2[(size_t)idxl[i >> 9] * 512 + (i & 511)];
}

__global__ __launch_bounds__(256)
void transpose_all(const float* __restrict__ w1, const float* __restrict__ w2,
                   unsigned short* __restrict__ w1t, unsigned short* __restrict__ w2t,
                   const int* __restrict__ idx) {
  __shared__ float tl[64][65];
  const int tid = threadIdx.x;
  const int ty = tid >> 6, tx = tid & 63;
  const int z = blockIdx.z;
  const float* src; unsigned short* dbase; int C, dstLd, r0, c0;
  if (z < 4) {
    src = w1 + (size_t)idx[z] * 512 * 2048;
    dbase = w1t + (size_t)z * 2048 * 512;
    C = 2048; dstLd = 512;
    r0 = blockIdx.x * 64; c0 = blockIdx.y * 64;
  } else {
    src = w2 + (size_t)idx[z - 4] * 2048 * 512;
    dbase = w2t + (size_t)(z - 4) * 2048;
    C = 512; dstLd = 8192;
    r0 = blockIdx.y * 64; c0 = blockIdx.x * 64;
  }
#pragma unroll
  for (int i = 0; i < 16; i++) {
    int r = ty * 16 + i;
    tl[r][tx] = src[(size_t)(r0 + r) * C + c0 + tx];
  }
  __syncthreads();
#pragma unroll
  for (int i = 0; i < 16; i++) {
    int rr = ty * 16 + i;
    dbase[(size_t)(c0 + rr) * dstLd + r0 + tx] = f2bf(tl[tx][rr]);
  }
}

__global__ __launch_bounds__(256)
void gate_softmax_xconv(const float* __restrict__ x,
                        const float* __restrict__ gate_w,
                        const float* __restrict__ gate_b,
                        const int* __restrict__ idx,
                        float* __restrict__ gwout,
                        unsigned short* __restrict__ xbf) {
  __shared__ float wsel[4][512];
  __shared__ float bsel[4];
  const int tid = threadIdx.x;
  for (int i = tid; i < 2048; i += 256) {
    int k = i >> 9;
    wsel[k][i & 511] = gate_w[(size_t)idx[k] * 512 + (i & 511)];
  }
  if (tid < 4) bsel[tid] = gate_b[idx[tid]];
  __syncthreads();
  const int wave = tid >> 6, lane = tid & 63;
  const int t = blockIdx.x * 4 + wave;
  const float* xr = x + (size_t)t * 512 + lane * 8;
  float4 v0 = ((const float4*)xr)[0];
  float4 v1 = ((const float4*)xr)[1];
  float vals[8] = {v0.x, v0.y, v0.z, v0.w, v1.x, v1.y, v1.z, v1.w};
  short8 pk;
#pragma unroll
  for (int j = 0; j < 8; j++) pk[j] = (short)f2bf(vals[j]);
  *(short8*)(xbf + (size_t)t * 512 + lane * 8) = pk;
  float a0 = 0.f, a1 = 0.f, a2 = 0.f, a3 = 0.f;
  const int dbase = lane * 8;
#pragma unroll
  for (int j = 0; j < 8; j++) {
    float xv = vals[j];
    a0 += xv * wsel[0][dbase + j];
    a1 += xv * wsel[1][dbase + j];
    a2 += xv * wsel[2][dbase + j];
    a3 += xv * wsel[3][dbase + j];
  }
#pragma unroll
  for (int off = 32; off >= 1; off >>= 1) {
    a0 += __shfl_down(a0, off, 64);
    a1 += __shfl_down(a1, off, 64);
    a2 += __shfl_down(a2, off, 64);
    a3 += __shfl_down(a3, off, 64);
  }
  if (lane == 0) {
    float l0 = a0 + bsel[0], l1 = a1 + bsel[1], l2 = a2 + bsel[2], l3 = a3 + bsel[3];
    float m = fmaxf(fmaxf(l0, l1), fmaxf(l2, l3));
    float e0 = __expf(l0 - m), e1 = __expf(l1 - m);
    float e2 = __expf(l2 - m), e3 = __expf(l3 - m);
    float inv = 1.0f / (e0 + e1 + e2 + e3);
    float* o = gwout + (size_t)t * 4;
    o[0] = e0 * inv; o[1] = e1 * inv; o[2] = e2 * inv; o[3] = e3 * inv;
  }
}

// ---------------- main GEMM: 8-phase double-buffered 256-row tile ----------------
// C[M x N] = A[M x K(lda)] * Bt[N x K(ldb)]^T, bf16 inputs, K-contiguous rows.
// BM=256, BN=NFREP*64, BK=64. 512 threads = 8 waves (2M x 4N). Per-wave out
// 128 x NFREP*16. Two K-tiles per iteration (buf0=even, buf1=odd; fixed roles).
// Phase = {ds_read frag subtile || issue half-tile global_load_lds} ->
//   s_barrier -> lgkmcnt(0) -> setprio(1) 2*NF2*4 MFMA setprio(0) -> s_barrier.
// Counted vmcnt at p3/p7 only (FIFO-derived); vmcnt(0) only in the peeled
// last iteration. Store/read-side XOR swizzle identical to the prior kernel
// (measured 0 bank conflicts).
//
// Stage/free schedule (trailing barrier of phase p frees region read at p):
//   p1: buf0.B-nh0   [nh0 read p0 -> regs held to p3]
//   p2: buf0.B-nh1   [read p1]
//   p3: buf0.A-mh0   [read p0]         + vmcnt(6|4)  (buf1 tile landed)
//   p4: buf0.A-mh1   [read p2]
//   p5: buf1.B-nh0   [read p4]
//   p6: buf1.B-nh1   [read p5]
//   p7: buf1.A-mh0 + A-mh1 [read p4/p6] + vmcnt(8|6) (buf0 next tile landed)

#define CFENCE asm volatile("" ::: "memory")
#define BAR    do { CFENCE; __builtin_amdgcn_s_barrier(); CFENCE; } while (0)
#define LGKM0  do { asm volatile("s_waitcnt lgkmcnt(0)" ::: "memory"); \
                    __builtin_amdgcn_sched_barrier(0); } while (0)
#define VMW(n) asm volatile("s_waitcnt vmcnt(" #n ")" ::: "memory")

#define LDA(abuf, mh)                                                       \
  do {                                                                      \
    _Pragma("unroll")                                                       \
    for (int m_ = 0; m_ < 4; m_++)                                          \
      _Pragma("unroll")                                                     \
      for (int ks_ = 0; ks_ < 2; ks_++)                                     \
        aF[m_][ks_] = *(const short8*)((abuf) +                             \
            (size_t)(wr * 128 + ((mh) * 4 + m_) * 16 + fr) * 64 +           \
            (((ks_ * 4 + quad) ^ swz) * 8));                                \
  } while (0)

#define LDB(bbuf, nh)                                                       \
  do {                                                                      \
    _Pragma("unroll")                                                       \
    for (int n_ = 0; n_ < NF2; n_++)                                        \
      _Pragma("unroll")                                                     \
      for (int ks_ = 0; ks_ < 2; ks_++)                                     \
        bF[nh][n_][ks_] = *(const short8*)((bbuf) +                         \
            (size_t)(wc * NWV + ((nh) * NF2 + n_) * 16 + fr) * 64 +         \
            (((ks_ * 4 + quad) ^ swz) * 8));                                \
  } while (0)

#define MM(mh, nh)                                                          \
  do {                                                                      \
    __builtin_amdgcn_s_setprio(1);                                          \
    _Pragma("unroll")                                                       \
    for (int m_ = 0; m_ < 4; m_++)                                          \
      _Pragma("unroll")                                                     \
      for (int n_ = 0; n_ < NF2; n_++)                                      \
        _Pragma("unroll")                                                   \
        for (int ks_ = 0; ks_ < 2; ks_++)                                   \
          acc[(mh) * 4 + m_][(nh) * NF2 + n_] =                             \
              __builtin_amdgcn_mfma_f32_16x16x32_bf16(                      \
                  aF[m_][ks_], bF[nh][n_][ks_],                             \
                  acc[(mh) * 4 + m_][(nh) * NF2 + n_], 0, 0, 0);            \
    __builtin_amdgcn_s_setprio(0);                                          \
  } while (0)

template <int NFREP, int EPI>
__global__ __launch_bounds__(512, 2)
void gemm8p(const unsigned short* __restrict__ A,
            const unsigned short* __restrict__ Bt,
            void* __restrict__ C, int K, int lda, int ldb, int ldc,
            const float* __restrict__ gw,
            const float* __restrict__ bias, int colOff, int accum, int doswz) {
  constexpr int BM = 256;
  constexpr int BN = NFREP * 64;
  constexpr int NWV = NFREP * 16;
  constexpr int NF2 = NFREP / 2;
  __shared__ unsigned short lds[2 * (BM * 64 + BN * 64)];

  const int tid = threadIdx.x;
  const int wave = tid >> 6, lane = tid & 63;
  const int lrow = lane >> 3, lslot = lane & 7, gch = lslot ^ lrow;
  const int wr = wave >> 2, wc = wave & 3;
  const int fr = lane & 15, quad = lane >> 4, swz = fr & 7;

  int bx = blockIdx.x, by = blockIdx.y;
  if (doswz) {   // bijective XCD swizzle; requires nwg % 8 == 0
    int nwg = gridDim.x * gridDim.y;
    int lin = by * gridDim.x + bx;
    int sw = (lin & 7) * (nwg >> 3) + (lin >> 3);
    bx = sw % gridDim.x; by = sw / gridDim.x;
  }
  const int rowA0 = bx * BM;
  const int rowB0 = by * BN;

  unsigned short* const A0 = lds;
  unsigned short* const B0 = lds + BM * 64;
  unsigned short* const A1 = lds + (BM * 64 + BN * 64);
  unsigned short* const B1 = A1 + BM * 64;

  // stage one A m-half unit (2 loads/thread): row-groups h*8+wave, h*8+wave+16
  auto stA = [&](unsigned short* ab, int h, int kt) {
#pragma unroll
    for (int j = 0; j < 2; j++) {
      int rg = h * 8 + wave + j * 16;
      const unsigned short* gp =
          A + (size_t)(rowA0 + rg * 8 + lrow) * lda + kt + gch * 8;
      __builtin_amdgcn_global_load_lds(AS1U32(gp), AS3U32(ab + rg * 512), 16, 0, 0);
    }
  };
  // stage one B n-half unit (2 loads/thread at NFREP=4, 1 at NFREP=2)
  auto stB = [&](unsigned short* bb, int nh, int kt) {
    if constexpr (NFREP == 4) {
#pragma unroll
      for (int j = 0; j < 2; j++) {
        int idx = j * 8 + wave;
        int rg = (idx >> 2) * 8 + (idx & 3) + nh * 4;
        const unsigned short* gp =
            Bt + (size_t)(rowB0 + rg * 8 + lrow) * ldb + kt + gch * 8;
        __builtin_amdgcn_global_load_lds(AS1U32(gp), AS3U32(bb + rg * 512), 16, 0, 0);
      }
    } else {
      int rg = (wave >> 1) * 4 + (wave & 1) + nh * 2;
      const unsigned short* gp =
          Bt + (size_t)(rowB0 + rg * 8 + lrow) * ldb + kt + gch * 8;
      __builtin_amdgcn_global_load_lds(AS1U32(gp), AS3U32(bb + rg * 512), 16, 0, 0);
    }
  };

  f32x4 acc[8][NFREP];
#pragma unroll
  for (int i = 0; i < 8; i++)
#pragma unroll
    for (int j = 0; j < NFREP; j++) acc[i][j] = (f32x4){0.f, 0.f, 0.f, 0.f};

  short8 aF[4][2];
  short8 bF[2][NF2][2];

  // ---- prologue: stage tile0 -> buf0, tile1 -> buf1 (issue order matters) ----
  stB(B0, 0, 0); stB(B0, 1, 0); stA(A0, 0, 0); stA(A0, 1, 0);
  stB(B1, 0, 64); stB(B1, 1, 64); stA(A1, 0, 64); stA(A1, 1, 64);
  if constexpr (NFREP == 4) VMW(8); else VMW(6);   // tile0 landed
  BAR;

  const int niter = K >> 7;   // K/128, two K-tiles per iteration
  for (int i = 0; i < niter - 1; i++) {
    const int kt = i * 128;
    // p0
    LDA(A0, 0); LDB(B0, 0);
    BAR; LGKM0; MM(0, 0); BAR;
    // p1
    LDB(B0, 1); stB(B0, 0, kt + 128);
    BAR; LGKM0; MM(0, 1); BAR;
    // p2
    LDA(A0, 1); stB(B0, 1, kt + 128);
    BAR; LGKM0; MM(1, 1); BAR;
    // p3
    stA(A0, 0, kt + 128);
    BAR; LGKM0; MM(1, 0);
    if constexpr (NFREP == 4) VMW(6); else VMW(4);  // buf1 current tile landed
    BAR;
    // p4
    LDA(A1, 0); LDB(B1, 0); stA(A0, 1, kt + 128);
    BAR; LGKM0; MM(0, 0); BAR;
    // p5
    LDB(B1, 1); stB(B1, 0, kt + 192);
    BAR; LGKM0; MM(0, 1); BAR;
    // p6
    LDA(A1, 1); stB(B1, 1, kt + 192);
    BAR; LGKM0; MM(1, 1); BAR;
    // p7
    stA(A1, 0, kt + 192); stA(A1, 1, kt + 192);
    BAR; LGKM0; MM(1, 0);
    if constexpr (NFREP == 4) VMW(8); else VMW(6);  // buf0 next tile landed
    BAR;
  }
  // ---- peeled last iteration (no staging; full drain before buf1) ----
  LDA(A0, 0); LDB(B0, 0); BAR; LGKM0; MM(0, 0); BAR;
  LDB(B0, 1);             BAR; LGKM0; MM(0, 1); BAR;
  LDA(A0, 1);             BAR; LGKM0; MM(1, 1); BAR;
                          BAR; LGKM0; MM(1, 0); VMW(0); BAR;
  LDA(A1, 0); LDB(B1, 0); BAR; LGKM0; MM(0, 0); BAR;
  LDB(B1, 1);             BAR; LGKM0; MM(0, 1); BAR;
  LDA(A1, 1);             BAR; LGKM0; MM(1, 1); BAR;
                          BAR; LGKM0; MM(1, 0);

  // ---- epilogue ----
  if (EPI == 1) {
    unsigned short* Cb = (unsigned short*)C;
    const int kexp = (colOff + rowB0) >> 11;   // 256 | 2048, so uniform per tile
#pragma unroll
    for (int m = 0; m < 8; m++) {
#pragma unroll
      for (int reg = 0; reg < 4; reg++) {
        int r = rowA0 + wr * 128 + m * 16 + quad * 4 + reg;
        float g = gw[(size_t)r * 4 + kexp];
#pragma unroll
        for (int n = 0; n < NFREP; n++) {
          int col = rowB0 + wc * NWV + n * 16 + fr;
          float v = acc[m][n][reg] + bias[colOff + col];
          Cb[(size_t)r * ldc + col] = f2bf(gelu_fast(v) * g);
        }
      }
    }
  } else {
    float* Cf = (float*)C;
#pragma unroll
    for (int m = 0; m < 8; m++) {
#pragma unroll
      for (int reg = 0; reg < 4; reg++) {
        int r = rowA0 + wr * 128 + m * 16 + quad * 4 + reg;
        size_t t4 = (size_t)r * 4;
        float g0 = gw[t4], g1 = gw[t4 + 1], g2 = gw[t4 + 2], g3 = gw[t4 + 3];
#pragma unroll
        for (int n = 0; n < NFREP; n++) {
          int col = rowB0 + wc * NWV + n * 16 + fr;
          size_t ci = (size_t)r * 512 + col;
          float v = acc[m][n][reg];
          if (accum) v += Cf[ci];
          else v += g0 * bias[col] + g1 * bias[512 + col] +
                    g2 * bias[1024 + col] + g3 * bias[1536 + col];
          Cf[ci] = v;
        }
      }
    }
  }
}

#undef LDA
#undef LDB
#undef MM

// ---------------- launch ----------------

extern "C" void kernel_launch(void* const* d_in, const int* in_sizes, int n_in,
                              void* d_out, int out_size, void* d_ws, size_t ws_size,
                              hipStream_t stream) {
  (void)in_sizes; (void)n_in; (void)out_size;
  const float* x      = (const float*)d_in[0];
  const float* gate_w = (const float*)d_in[1];
  const float* gate_b = (const float*)d_in[2];
  const float* w1     = (const float*)d_in[3];
  const float* b1     = (const float*)d_in[4];
  const float* w2     = (const float*)d_in[5];
  const float* b2     = (const float*)d_in[6];

  char* ws = (char*)d_ws;
  int*            idx   = (int*)(ws + 0);                //  16 B
  float*          gw    = (float*)(ws + 4096);           // 256 KB  [T,4]
  float*          b1cat = (float*)(ws + 266240);         //  32 KB
  float*          b2sel = (float*)(ws + 299008);         //   8 KB
  float*          kpart = (float*)(ws + 307200);         // 512 KB  [256,512]
  unsigned short* xbf   = (unsigned short*)(ws + 831488);      // 16.8 MB [T,512]
  unsigned short* w1t   = (unsigned short*)(ws + 17608704);    //  8.4 MB [8192,512]
  unsigned short* w2t   = (unsigned short*)(ws + 25997312);    //  8.4 MB [512,8192]
  unsigned short* hbuf  = (unsigned short*)(ws + 34385920);    // h' slab
  const size_t HBUF_OFF = 34385920;

  size_t avail = ws_size > HBUF_OFF ? ws_size - HBUF_OFF : 0;
  int nslab = 1;
  while (nslab < 16 && (size_t)16384 * (8192 / nslab) * 2 > avail) nslab <<= 1;
  const int slabDF = 8192 / nslab;

  reduce_part<<<256, 512, 0, stream>>>(x, kpart);
  gate_all<<<1, 1024, 0, stream>>>(kpart, gate_w, gate_b, b1, b2, idx, b1cat, b2sel);
  transpose_all<<<dim3(8, 32, 8), 256, 0, stream>>>(w1, w2, w1t, w2t, idx);
  gate_softmax_xconv<<<4096, 256, 0, stream>>>(x, gate_w, gate_b, idx, gw, xbf);

  for (int s = 0; s < nslab; s++) {
    const int c0 = s * slabDF;
    // gemm1: [16384 x 512] @ [slabDF x 512]^T -> bf16 h' (gelu+gw fused)
    gemm8p<4, 1><<<dim3(64, slabDF / 256), 512, 0, stream>>>(
        xbf, w1t + (size_t)c0 * 512, hbuf,
        /*K=*/512, /*lda=*/512, /*ldb=*/512, /*ldc=*/slabDF,
        gw, b1cat, c0, 0, 0);
    // gemm2: [16384 x slabDF] @ [512 x slabDF(ldb 8192)]^T -> f32 out (+accum)
    gemm8p<2, 2><<<dim3(64, 4), 512, 0, stream>>>(
        hbuf, w2t + c0, (float*)d_out,
        /*K=*/slabDF, /*lda=*/slabDF, /*ldb=*/8192, /*ldc=*/512,
        gw, b2sel, 0, s > 0, 1);
  }
}

// Round 2
// 553.288 us; speedup vs baseline: 1.0109x; 1.0109x over previous
//
#include <hip/hip_runtime.h>
#include <hip/hip_bf16.h>
#include <cstdint>
#include <cstddef>

typedef __attribute__((ext_vector_type(8))) short short8;
typedef __attribute__((ext_vector_type(4))) float f32x4;

#define AS1U32(p) ((const __attribute__((address_space(1))) uint32_t*)(p))
#define AS3U32(p) ((__attribute__((address_space(3))) uint32_t*)(p))

__device__ __forceinline__ unsigned short f2bf(float v) {
  union { float f; uint32_t u; } a; a.f = v;
  uint32_t u = a.u;
  u += 0x7FFFu + ((u >> 16) & 1u);   // round-to-nearest-even
  return (unsigned short)(u >> 16);
}

// gelu(x) = x * sigmoid(2u), u = sqrt(2/pi)(x + 0.044715 x^3)
__device__ __forceinline__ float gelu_fast(float x) {
  const float c0 = 0.7978845608028654f;
  const float c1 = 0.044715f;
  float u = c0 * (x + c1 * x * x * x);
  return x * __builtin_amdgcn_rcpf(1.0f + __expf(-2.0f * u));
}

// ---------------- prologue kernels (unchanged) ----------------

__global__ __launch_bounds__(512)
void reduce_part(const float* __restrict__ x, float* __restrict__ kpart) {
  const int d = threadIdx.x;
  const int b = blockIdx.x;
  float s = 0.f;
#pragma unroll 4
  for (int i = 0; i < 64; i++)
    s += x[((size_t)b * 64 + i) * 512 + d];
  kpart[(size_t)b * 512 + d] = s;
}

__global__ __launch_bounds__(1024)
void gate_all(const float* __restrict__ kpart,
              const float* __restrict__ gate_w,
              const float* __restrict__ gate_b,
              const float* __restrict__ b1, const float* __restrict__ b2,
              int* __restrict__ idxout,
              float* __restrict__ b1cat, float* __restrict__ b2sel) {
  __shared__ float ksum2[2][512];
  __shared__ float coarse[16];
  __shared__ int idxl[4];
  const int t = threadIdx.x;
  {
    const int d = t & 511, h = t >> 9;
    float s = 0.f;
    for (int p = h * 128; p < h * 128 + 128; p++) s += kpart[(size_t)p * 512 + d];
    ksum2[h][d] = s;
  }
  __syncthreads();
  {
    const int wave = t >> 6, lane = t & 63;
    const int d0 = lane * 8;
    float s = 0.f;
#pragma unroll
    for (int j = 0; j < 8; j++)
      s += gate_w[wave * 512 + d0 + j] * (ksum2[0][d0 + j] + ksum2[1][d0 + j]);
#pragma unroll
    for (int off = 32; off >= 1; off >>= 1) s += __shfl_down(s, off, 64);
    if (lane == 0) coarse[wave] = s + gate_b[wave];
  }
  __syncthreads();
  if (t == 0) {
    unsigned taken = 0;
    for (int r = 0; r < 4; r++) {
      float best = -3.4e38f; int bi = 0;
      for (int e = 0; e < 16; e++)
        if (!((taken >> e) & 1u) && coarse[e] > best) { best = coarse[e]; bi = e; }
      taken |= 1u << bi;
      idxl[r] = bi; idxout[r] = bi;
    }
  }
  __syncthreads();
  for (int i = t; i < 8192; i += 1024)
    b1cat[i] = b1[(size_t)idxl[i >> 11] * 2048 + (i & 2047)];
  for (int i = t; i < 2048; i += 1024)
    b2sel[i] = b2[(size_t)idxl[i >> 9] * 512 + (i & 511)];
}

__global__ __launch_bounds__(256)
void transpose_all(const float* __restrict__ w1, const float* __restrict__ w2,
                   unsigned short* __restrict__ w1t, unsigned short* __restrict__ w2t,
                   const int* __restrict__ idx) {
  __shared__ float tl[64][65];
  const int tid = threadIdx.x;
  const int ty = tid >> 6, tx = tid & 63;
  const int z = blockIdx.z;
  const float* src; unsigned short* dbase; int C, dstLd, r0, c0;
  if (z < 4) {
    src = w1 + (size_t)idx[z] * 512 * 2048;
    dbase = w1t + (size_t)z * 2048 * 512;
    C = 2048; dstLd = 512;
    r0 = blockIdx.x * 64; c0 = blockIdx.y * 64;
  } else {
    src = w2 + (size_t)idx[z - 4] * 2048 * 512;
    dbase = w2t + (size_t)(z - 4) * 2048;
    C = 512; dstLd = 8192;
    r0 = blockIdx.y * 64; c0 = blockIdx.x * 64;
  }
#pragma unroll
  for (int i = 0; i < 16; i++) {
    int r = ty * 16 + i;
    tl[r][tx] = src[(size_t)(r0 + r) * C + c0 + tx];
  }
  __syncthreads();
#pragma unroll
  for (int i = 0; i < 16; i++) {
    int rr = ty * 16 + i;
    dbase[(size_t)(c0 + rr) * dstLd + r0 + tx] = f2bf(tl[tx][rr]);
  }
}

__global__ __launch_bounds__(256)
void gate_softmax_xconv(const float* __restrict__ x,
                        const float* __restrict__ gate_w,
                        const float* __restrict__ gate_b,
                        const int* __restrict__ idx,
                        float* __restrict__ gwout,
                        unsigned short* __restrict__ xbf) {
  __shared__ float wsel[4][512];
  __shared__ float bsel[4];
  const int tid = threadIdx.x;
  for (int i = tid; i < 2048; i += 256) {
    int k = i >> 9;
    wsel[k][i & 511] = gate_w[(size_t)idx[k] * 512 + (i & 511)];
  }
  if (tid < 4) bsel[tid] = gate_b[idx[tid]];
  __syncthreads();
  const int wave = tid >> 6, lane = tid & 63;
  const int t = blockIdx.x * 4 + wave;
  const float* xr = x + (size_t)t * 512 + lane * 8;
  float4 v0 = ((const float4*)xr)[0];
  float4 v1 = ((const float4*)xr)[1];
  float vals[8] = {v0.x, v0.y, v0.z, v0.w, v1.x, v1.y, v1.z, v1.w};
  short8 pk;
#pragma unroll
  for (int j = 0; j < 8; j++) pk[j] = (short)f2bf(vals[j]);
  *(short8*)(xbf + (size_t)t * 512 + lane * 8) = pk;
  float a0 = 0.f, a1 = 0.f, a2 = 0.f, a3 = 0.f;
  const int dbase = lane * 8;
#pragma unroll
  for (int j = 0; j < 8; j++) {
    float xv = vals[j];
    a0 += xv * wsel[0][dbase + j];
    a1 += xv * wsel[1][dbase + j];
    a2 += xv * wsel[2][dbase + j];
    a3 += xv * wsel[3][dbase + j];
  }
#pragma unroll
  for (int off = 32; off >= 1; off >>= 1) {
    a0 += __shfl_down(a0, off, 64);
    a1 += __shfl_down(a1, off, 64);
    a2 += __shfl_down(a2, off, 64);
    a3 += __shfl_down(a3, off, 64);
  }
  if (lane == 0) {
    float l0 = a0 + bsel[0], l1 = a1 + bsel[1], l2 = a2 + bsel[2], l3 = a3 + bsel[3];
    float m = fmaxf(fmaxf(l0, l1), fmaxf(l2, l3));
    float e0 = __expf(l0 - m), e1 = __expf(l1 - m);
    float e2 = __expf(l2 - m), e3 = __expf(l3 - m);
    float inv = 1.0f / (e0 + e1 + e2 + e3);
    float* o = gwout + (size_t)t * 4;
    o[0] = e0 * inv; o[1] = e1 * inv; o[2] = e2 * inv; o[3] = e3 * inv;
  }
}

// ---------------- gemm_bt: 128x128 2-barrier kernel (round-0 proven) ----------------
// Used for gemm1 (K=512, short-K, epilogue-heavy): 32 KiB LDS -> 2 blocks/CU,
// so one block's gelu epilogue overlaps another block's MFMA.
template <int EPI>
__global__ __launch_bounds__(256, 2)
void gemm_bt(const unsigned short* __restrict__ A,
             const unsigned short* __restrict__ Bt,
             void* __restrict__ C, int K, int lda, int ldb, int ldc,
             const float* __restrict__ gw,
             const float* __restrict__ bias, int colOff, int accum) {
  __shared__ unsigned short lA[128 * 64];
  __shared__ unsigned short lB[128 * 64];
  const int tid = threadIdx.x;
  const int wave = tid >> 6;
  const int lane = tid & 63;
  const int rowA0 = blockIdx.x * 128;
  const int rowB0 = blockIdx.y * 128;

  f32x4 acc[4][4];
#pragma unroll
  for (int i = 0; i < 4; i++)
#pragma unroll
    for (int j = 0; j < 4; j++) acc[i][j] = (f32x4){0.f, 0.f, 0.f, 0.f};

  const int lrow = lane >> 3;
  const int lslot = lane & 7;
  const int gchunk = lslot ^ lrow;
  const int fr = lane & 15;
  const int quad = lane >> 4;
  const int wm = (wave >> 1) * 64;
  const int wn = (wave & 1) * 64;
  const int swz = fr & 7;

  for (int kt = 0; kt < K; kt += 64) {
#pragma unroll
    for (int c = 0; c < 4; c++) {
      int r = wave * 32 + c * 8 + lrow;
      const unsigned short* gp = A + (size_t)(rowA0 + r) * lda + kt + gchunk * 8;
      __builtin_amdgcn_global_load_lds(AS1U32(gp), AS3U32(lA + (wave * 32 + c * 8) * 64), 16, 0, 0);
    }
#pragma unroll
    for (int c = 0; c < 4; c++) {
      int r = wave * 32 + c * 8 + lrow;
      const unsigned short* gp = Bt + (size_t)(rowB0 + r) * ldb + kt + gchunk * 8;
      __builtin_amdgcn_global_load_lds(AS1U32(gp), AS3U32(lB + (wave * 32 + c * 8) * 64), 16, 0, 0);
    }
    __syncthreads();
#pragma unroll
    for (int ks = 0; ks < 2; ks++) {
      short8 af[4], bfr[4];
      const int c = ks * 4 + quad;
      const int slot = (c ^ swz) << 3;
#pragma unroll
      for (int i = 0; i < 4; i++)
        af[i] = *(const short8*)(lA + (wm + i * 16 + fr) * 64 + slot);
#pragma unroll
      for (int j = 0; j < 4; j++)
        bfr[j] = *(const short8*)(lB + (wn + j * 16 + fr) * 64 + slot);
#pragma unroll
      for (int i = 0; i < 4; i++)
#pragma unroll
        for (int j = 0; j < 4; j++)
          acc[i][j] = __builtin_amdgcn_mfma_f32_16x16x32_bf16(af[i], bfr[j], acc[i][j], 0, 0, 0);
    }
    __syncthreads();
  }

  if (EPI == 1) {
    unsigned short* Cb = (unsigned short*)C;
    const int kexp = (colOff + rowB0) >> 11;
#pragma unroll
    for (int i = 0; i < 4; i++) {
#pragma unroll
      for (int reg = 0; reg < 4; reg++) {
        int r = rowA0 + wm + i * 16 + quad * 4 + reg;
        float g = gw[(size_t)r * 4 + kexp];
#pragma unroll
        for (int j = 0; j < 4; j++) {
          int n = rowB0 + wn + j * 16 + fr;
          float v = acc[i][j][reg] + bias[colOff + n];
          Cb[(size_t)r * ldc + n] = f2bf(gelu_fast(v) * g);
        }
      }
    }
  } else {
    float* Cf = (float*)C;
#pragma unroll
    for (int i = 0; i < 4; i++) {
#pragma unroll
      for (int reg = 0; reg < 4; reg++) {
        int r = rowA0 + wm + i * 16 + quad * 4 + reg;
        size_t t4 = (size_t)r * 4;
        float g0 = gw[t4], g1 = gw[t4 + 1], g2 = gw[t4 + 2], g3 = gw[t4 + 3];
#pragma unroll
        for (int j = 0; j < 4; j++) {
          int n = rowB0 + wn + j * 16 + fr;
          size_t ci = (size_t)r * 512 + n;
          float v = acc[i][j][reg];
          if (accum) v += Cf[ci];
          else v += g0 * bias[n] + g1 * bias[512 + n] +
                    g2 * bias[1024 + n] + g3 * bias[1536 + n];
          Cf[ci] = v;
        }
      }
    }
  }
}

// ---------------- gemm8p: 8-phase double-buffered 256-row tile ----------------
// Used for gemm2 (long K = slabDF): counted-vmcnt pipeline, proven ~1.25 PF.

#define CFENCE asm volatile("" ::: "memory")
#define BAR    do { CFENCE; __builtin_amdgcn_s_barrier(); CFENCE; } while (0)
#define LGKM0  do { asm volatile("s_waitcnt lgkmcnt(0)" ::: "memory"); \
                    __builtin_amdgcn_sched_barrier(0); } while (0)
#define VMW(n) asm volatile("s_waitcnt vmcnt(" #n ")" ::: "memory")

#define LDA(abuf, mh)                                                       \
  do {                                                                      \
    _Pragma("unroll")                                                       \
    for (int m_ = 0; m_ < 4; m_++)                                          \
      _Pragma("unroll")                                                     \
      for (int ks_ = 0; ks_ < 2; ks_++)                                     \
        aF[m_][ks_] = *(const short8*)((abuf) +                             \
            (size_t)(wr * 128 + ((mh) * 4 + m_) * 16 + fr) * 64 +           \
            (((ks_ * 4 + quad) ^ swz) * 8));                                \
  } while (0)

#define LDB(bbuf, nh)                                                       \
  do {                                                                      \
    _Pragma("unroll")                                                       \
    for (int n_ = 0; n_ < NF2; n_++)                                        \
      _Pragma("unroll")                                                     \
      for (int ks_ = 0; ks_ < 2; ks_++)                                     \
        bF[nh][n_][ks_] = *(const short8*)((bbuf) +                         \
            (size_t)(wc * NWV + ((nh) * NF2 + n_) * 16 + fr) * 64 +         \
            (((ks_ * 4 + quad) ^ swz) * 8));                                \
  } while (0)

#define MM(mh, nh)                                                          \
  do {                                                                      \
    __builtin_amdgcn_s_setprio(1);                                          \
    _Pragma("unroll")                                                       \
    for (int m_ = 0; m_ < 4; m_++)                                          \
      _Pragma("unroll")                                                     \
      for (int n_ = 0; n_ < NF2; n_++)                                      \
        _Pragma("unroll")                                                   \
        for (int ks_ = 0; ks_ < 2; ks_++)                                   \
          acc[(mh) * 4 + m_][(nh) * NF2 + n_] =                             \
              __builtin_amdgcn_mfma_f32_16x16x32_bf16(                      \
                  aF[m_][ks_], bF[nh][n_][ks_],                             \
                  acc[(mh) * 4 + m_][(nh) * NF2 + n_], 0, 0, 0);            \
    __builtin_amdgcn_s_setprio(0);                                          \
  } while (0)

template <int NFREP, int EPI>
__global__ __launch_bounds__(512, 2)
void gemm8p(const unsigned short* __restrict__ A,
            const unsigned short* __restrict__ Bt,
            void* __restrict__ C, int K, int lda, int ldb, int ldc,
            const float* __restrict__ gw,
            const float* __restrict__ bias, int colOff, int accum, int doswz) {
  constexpr int BM = 256;
  constexpr int BN = NFREP * 64;
  constexpr int NWV = NFREP * 16;
  constexpr int NF2 = NFREP / 2;
  __shared__ unsigned short lds[2 * (BM * 64 + BN * 64)];

  const int tid = threadIdx.x;
  const int wave = tid >> 6, lane = tid & 63;
  const int lrow = lane >> 3, lslot = lane & 7, gch = lslot ^ lrow;
  const int wr = wave >> 2, wc = wave & 3;
  const int fr = lane & 15, quad = lane >> 4, swz = fr & 7;

  int bx = blockIdx.x, by = blockIdx.y;
  if (doswz) {   // bijective XCD swizzle; requires nwg % 8 == 0
    int nwg = gridDim.x * gridDim.y;
    int lin = by * gridDim.x + bx;
    int sw = (lin & 7) * (nwg >> 3) + (lin >> 3);
    bx = sw % gridDim.x; by = sw / gridDim.x;
  }
  const int rowA0 = bx * BM;
  const int rowB0 = by * BN;

  unsigned short* const A0 = lds;
  unsigned short* const B0 = lds + BM * 64;
  unsigned short* const A1 = lds + (BM * 64 + BN * 64);
  unsigned short* const B1 = A1 + BM * 64;

  auto stA = [&](unsigned short* ab, int h, int kt) {
#pragma unroll
    for (int j = 0; j < 2; j++) {
      int rg = h * 8 + wave + j * 16;
      const unsigned short* gp =
          A + (size_t)(rowA0 + rg * 8 + lrow) * lda + kt + gch * 8;
      __builtin_amdgcn_global_load_lds(AS1U32(gp), AS3U32(ab + rg * 512), 16, 0, 0);
    }
  };
  auto stB = [&](unsigned short* bb, int nh, int kt) {
    if constexpr (NFREP == 4) {
#pragma unroll
      for (int j = 0; j < 2; j++) {
        int idx = j * 8 + wave;
        int rg = (idx >> 2) * 8 + (idx & 3) + nh * 4;
        const unsigned short* gp =
            Bt + (size_t)(rowB0 + rg * 8 + lrow) * ldb + kt + gch * 8;
        __builtin_amdgcn_global_load_lds(AS1U32(gp), AS3U32(bb + rg * 512), 16, 0, 0);
      }
    } else {
      int rg = (wave >> 1) * 4 + (wave & 1) + nh * 2;
      const unsigned short* gp =
          Bt + (size_t)(rowB0 + rg * 8 + lrow) * ldb + kt + gch * 8;
      __builtin_amdgcn_global_load_lds(AS1U32(gp), AS3U32(bb + rg * 512), 16, 0, 0);
    }
  };

  f32x4 acc[8][NFREP];
#pragma unroll
  for (int i = 0; i < 8; i++)
#pragma unroll
    for (int j = 0; j < NFREP; j++) acc[i][j] = (f32x4){0.f, 0.f, 0.f, 0.f};

  short8 aF[4][2];
  short8 bF[2][NF2][2];

  // ---- prologue: stage tile0 -> buf0, tile1 -> buf1 ----
  stB(B0, 0, 0); stB(B0, 1, 0); stA(A0, 0, 0); stA(A0, 1, 0);
  stB(B1, 0, 64); stB(B1, 1, 64); stA(A1, 0, 64); stA(A1, 1, 64);
  if constexpr (NFREP == 4) VMW(8); else VMW(6);   // tile0 landed
  BAR;

  const int niter = K >> 7;   // K/128, two K-tiles per iteration
  for (int i = 0; i < niter - 1; i++) {
    const int kt = i * 128;
    // p0
    LDA(A0, 0); LDB(B0, 0);
    BAR; LGKM0; MM(0, 0); BAR;
    // p1
    LDB(B0, 1); stB(B0, 0, kt + 128);
    BAR; LGKM0; MM(0, 1); BAR;
    // p2
    LDA(A0, 1); stB(B0, 1, kt + 128);
    BAR; LGKM0; MM(1, 1); BAR;
    // p3
    stA(A0, 0, kt + 128);
    BAR; LGKM0; MM(1, 0);
    if constexpr (NFREP == 4) VMW(6); else VMW(4);  // buf1 current tile landed
    BAR;
    // p4
    LDA(A1, 0); LDB(B1, 0); stA(A0, 1, kt + 128);
    BAR; LGKM0; MM(0, 0); BAR;
    // p5
    LDB(B1, 1); stB(B1, 0, kt + 192);
    BAR; LGKM0; MM(0, 1); BAR;
    // p6
    LDA(A1, 1); stB(B1, 1, kt + 192);
    BAR; LGKM0; MM(1, 1); BAR;
    // p7
    stA(A1, 0, kt + 192); stA(A1, 1, kt + 192);
    BAR; LGKM0; MM(1, 0);
    if constexpr (NFREP == 4) VMW(8); else VMW(6);  // buf0 next tile landed
    BAR;
  }
  // ---- peeled last iteration ----
  LDA(A0, 0); LDB(B0, 0); BAR; LGKM0; MM(0, 0); BAR;
  LDB(B0, 1);             BAR; LGKM0; MM(0, 1); BAR;
  LDA(A0, 1);             BAR; LGKM0; MM(1, 1); BAR;
                          BAR; LGKM0; MM(1, 0); VMW(0); BAR;
  LDA(A1, 0); LDB(B1, 0); BAR; LGKM0; MM(0, 0); BAR;
  LDB(B1, 1);             BAR; LGKM0; MM(0, 1); BAR;
  LDA(A1, 1);             BAR; LGKM0; MM(1, 1); BAR;
                          BAR; LGKM0; MM(1, 0);

  // ---- epilogue ----
  if (EPI == 1) {
    unsigned short* Cb = (unsigned short*)C;
    const int kexp = (colOff + rowB0) >> 11;
#pragma unroll
    for (int m = 0; m < 8; m++) {
#pragma unroll
      for (int reg = 0; reg < 4; reg++) {
        int r = rowA0 + wr * 128 + m * 16 + quad * 4 + reg;
        float g = gw[(size_t)r * 4 + kexp];
#pragma unroll
        for (int n = 0; n < NFREP; n++) {
          int col = rowB0 + wc * NWV + n * 16 + fr;
          float v = acc[m][n][reg] + bias[colOff + col];
          Cb[(size_t)r * ldc + col] = f2bf(gelu_fast(v) * g);
        }
      }
    }
  } else {
    float* Cf = (float*)C;
#pragma unroll
    for (int m = 0; m < 8; m++) {
#pragma unroll
      for (int reg = 0; reg < 4; reg++) {
        int r = rowA0 + wr * 128 + m * 16 + quad * 4 + reg;
        size_t t4 = (size_t)r * 4;
        float g0 = gw[t4], g1 = gw[t4 + 1], g2 = gw[t4 + 2], g3 = gw[t4 + 3];
#pragma unroll
        for (int n = 0; n < NFREP; n++) {
          int col = rowB0 + wc * NWV + n * 16 + fr;
          size_t ci = (size_t)r * 512 + col;
          float v = acc[m][n][reg];
          if (accum) v += Cf[ci];
          else v += g0 * bias[col] + g1 * bias[512 + col] +
                    g2 * bias[1024 + col] + g3 * bias[1536 + col];
          Cf[ci] = v;
        }
      }
    }
  }
}

#undef LDA
#undef LDB
#undef MM

// ---------------- launch ----------------

extern "C" void kernel_launch(void* const* d_in, const int* in_sizes, int n_in,
                              void* d_out, int out_size, void* d_ws, size_t ws_size,
                              hipStream_t stream) {
  (void)in_sizes; (void)n_in; (void)out_size;
  const float* x      = (const float*)d_in[0];
  const float* gate_w = (const float*)d_in[1];
  const float* gate_b = (const float*)d_in[2];
  const float* w1     = (const float*)d_in[3];
  const float* b1     = (const float*)d_in[4];
  const float* w2     = (const float*)d_in[5];
  const float* b2     = (const float*)d_in[6];

  char* ws = (char*)d_ws;
  int*            idx   = (int*)(ws + 0);                //  16 B
  float*          gw    = (float*)(ws + 4096);           // 256 KB  [T,4]
  float*          b1cat = (float*)(ws + 266240);         //  32 KB
  float*          b2sel = (float*)(ws + 299008);         //   8 KB
  float*          kpart = (float*)(ws + 307200);         // 512 KB  [256,512]
  unsigned short* xbf   = (unsigned short*)(ws + 831488);      // 16.8 MB [T,512]
  unsigned short* w1t   = (unsigned short*)(ws + 17608704);    //  8.4 MB [8192,512]
  unsigned short* w2t   = (unsigned short*)(ws + 25997312);    //  8.4 MB [512,8192]
  unsigned short* hbuf  = (unsigned short*)(ws + 34385920);    // h' slab
  const size_t HBUF_OFF = 34385920;

  size_t avail = ws_size > HBUF_OFF ? ws_size - HBUF_OFF : 0;
  int nslab = 1;
  while (nslab < 16 && (size_t)16384 * (8192 / nslab) * 2 > avail) nslab <<= 1;
  const int slabDF = 8192 / nslab;

  reduce_part<<<256, 512, 0, stream>>>(x, kpart);
  gate_all<<<1, 1024, 0, stream>>>(kpart, gate_w, gate_b, b1, b2, idx, b1cat, b2sel);
  transpose_all<<<dim3(8, 32, 8), 256, 0, stream>>>(w1, w2, w1t, w2t, idx);
  gate_softmax_xconv<<<4096, 256, 0, stream>>>(x, gate_w, gate_b, idx, gw, xbf);

  for (int s = 0; s < nslab; s++) {
    const int c0 = s * slabDF;
    // gemm1 (short K=512, gelu epilogue): proven 128^2 2-barrier structure,
    // 2 blocks/CU so epilogue overlaps other blocks' MFMA.
    gemm_bt<1><<<dim3(128, slabDF / 128), 256, 0, stream>>>(
        xbf, w1t + (size_t)c0 * 512, hbuf,
        /*K=*/512, /*lda=*/512, /*ldb=*/512, /*ldc=*/slabDF,
        gw, b1cat, c0, 0);
    // gemm2 (long K=slabDF): proven 8-phase counted-vmcnt structure.
    gemm8p<2, 2><<<dim3(64, 4), 512, 0, stream>>>(
        hbuf, w2t + c0, (float*)d_out,
        /*K=*/slabDF, /*lda=*/slabDF, /*ldb=*/8192, /*ldc=*/512,
        gw, b2sel, 0, s > 0, 1);
  }
}

// Round 3
// 534.083 us; speedup vs baseline: 1.0472x; 1.0360x over previous
//
#include <hip/hip_runtime.h>
#include <hip/hip_bf16.h>
#include <cstdint>
#include <cstddef>

typedef __attribute__((ext_vector_type(8))) short short8;
typedef __attribute__((ext_vector_type(4))) float f32x4;

#define AS1U32(p) ((const __attribute__((address_space(1))) uint32_t*)(p))
#define AS3U32(p) ((__attribute__((address_space(3))) uint32_t*)(p))

__device__ __forceinline__ unsigned short f2bf(float v) {
  union { float f; uint32_t u; } a; a.f = v;
  uint32_t u = a.u;
  u += 0x7FFFu + ((u >> 16) & 1u);   // round-to-nearest-even
  return (unsigned short)(u >> 16);
}

// gelu(x) = x * sigmoid(2u), u = sqrt(2/pi)(x + 0.044715 x^3)
__device__ __forceinline__ float gelu_fast(float x) {
  const float c0 = 0.7978845608028654f;
  const float c1 = 0.044715f;
  float u = c0 * (x + c1 * x * x * x);
  return x * __builtin_amdgcn_rcpf(1.0f + __expf(-2.0f * u));
}

// ---------------- prologue kernels (unchanged) ----------------

__global__ __launch_bounds__(512)
void reduce_part(const float* __restrict__ x, float* __restrict__ kpart) {
  const int d = threadIdx.x;
  const int b = blockIdx.x;
  float s = 0.f;
#pragma unroll 4
  for (int i = 0; i < 64; i++)
    s += x[((size_t)b * 64 + i) * 512 + d];
  kpart[(size_t)b * 512 + d] = s;
}

__global__ __launch_bounds__(1024)
void gate_all(const float* __restrict__ kpart,
              const float* __restrict__ gate_w,
              const float* __restrict__ gate_b,
              const float* __restrict__ b1, const float* __restrict__ b2,
              int* __restrict__ idxout,
              float* __restrict__ b1cat, float* __restrict__ b2sel) {
  __shared__ float ksum2[2][512];
  __shared__ float coarse[16];
  __shared__ int idxl[4];
  const int t = threadIdx.x;
  {
    const int d = t & 511, h = t >> 9;
    float s = 0.f;
    for (int p = h * 128; p < h * 128 + 128; p++) s += kpart[(size_t)p * 512 + d];
    ksum2[h][d] = s;
  }
  __syncthreads();
  {
    const int wave = t >> 6, lane = t & 63;
    const int d0 = lane * 8;
    float s = 0.f;
#pragma unroll
    for (int j = 0; j < 8; j++)
      s += gate_w[wave * 512 + d0 + j] * (ksum2[0][d0 + j] + ksum2[1][d0 + j]);
#pragma unroll
    for (int off = 32; off >= 1; off >>= 1) s += __shfl_down(s, off, 64);
    if (lane == 0) coarse[wave] = s + gate_b[wave];
  }
  __syncthreads();
  if (t == 0) {
    unsigned taken = 0;
    for (int r = 0; r < 4; r++) {
      float best = -3.4e38f; int bi = 0;
      for (int e = 0; e < 16; e++)
        if (!((taken >> e) & 1u) && coarse[e] > best) { best = coarse[e]; bi = e; }
      taken |= 1u << bi;
      idxl[r] = bi; idxout[r] = bi;
    }
  }
  __syncthreads();
  for (int i = t; i < 8192; i += 1024)
    b1cat[i] = b1[(size_t)idxl[i >> 11] * 2048 + (i & 2047)];
  for (int i = t; i < 2048; i += 1024)
    b2sel[i] = b2[(size_t)idxl[i >> 9] * 512 + (i & 511)];
}

__global__ __launch_bounds__(256)
void transpose_all(const float* __restrict__ w1, const float* __restrict__ w2,
                   unsigned short* __restrict__ w1t, unsigned short* __restrict__ w2t,
                   const int* __restrict__ idx) {
  __shared__ float tl[64][65];
  const int tid = threadIdx.x;
  const int ty = tid >> 6, tx = tid & 63;
  const int z = blockIdx.z;
  const float* src; unsigned short* dbase; int C, dstLd, r0, c0;
  if (z < 4) {
    src = w1 + (size_t)idx[z] * 512 * 2048;
    dbase = w1t + (size_t)z * 2048 * 512;
    C = 2048; dstLd = 512;
    r0 = blockIdx.x * 64; c0 = blockIdx.y * 64;
  } else {
    src = w2 + (size_t)idx[z - 4] * 2048 * 512;
    dbase = w2t + (size_t)(z - 4) * 2048;
    C = 512; dstLd = 8192;
    r0 = blockIdx.y * 64; c0 = blockIdx.x * 64;
  }
#pragma unroll
  for (int i = 0; i < 16; i++) {
    int r = ty * 16 + i;
    tl[r][tx] = src[(size_t)(r0 + r) * C + c0 + tx];
  }
  __syncthreads();
#pragma unroll
  for (int i = 0; i < 16; i++) {
    int rr = ty * 16 + i;
    dbase[(size_t)(c0 + rr) * dstLd + r0 + tx] = f2bf(tl[tx][rr]);
  }
}

__global__ __launch_bounds__(256)
void gate_softmax_xconv(const float* __restrict__ x,
                        const float* __restrict__ gate_w,
                        const float* __restrict__ gate_b,
                        const int* __restrict__ idx,
                        float* __restrict__ gwout,
                        unsigned short* __restrict__ xbf) {
  __shared__ float wsel[4][512];
  __shared__ float bsel[4];
  const int tid = threadIdx.x;
  for (int i = tid; i < 2048; i += 256) {
    int k = i >> 9;
    wsel[k][i & 511] = gate_w[(size_t)idx[k] * 512 + (i & 511)];
  }
  if (tid < 4) bsel[tid] = gate_b[idx[tid]];
  __syncthreads();
  const int wave = tid >> 6, lane = tid & 63;
  const int t = blockIdx.x * 4 + wave;
  const float* xr = x + (size_t)t * 512 + lane * 8;
  float4 v0 = ((const float4*)xr)[0];
  float4 v1 = ((const float4*)xr)[1];
  float vals[8] = {v0.x, v0.y, v0.z, v0.w, v1.x, v1.y, v1.z, v1.w};
  short8 pk;
#pragma unroll
  for (int j = 0; j < 8; j++) pk[j] = (short)f2bf(vals[j]);
  *(short8*)(xbf + (size_t)t * 512 + lane * 8) = pk;
  float a0 = 0.f, a1 = 0.f, a2 = 0.f, a3 = 0.f;
  const int dbase = lane * 8;
#pragma unroll
  for (int j = 0; j < 8; j++) {
    float xv = vals[j];
    a0 += xv * wsel[0][dbase + j];
    a1 += xv * wsel[1][dbase + j];
    a2 += xv * wsel[2][dbase + j];
    a3 += xv * wsel[3][dbase + j];
  }
#pragma unroll
  for (int off = 32; off >= 1; off >>= 1) {
    a0 += __shfl_down(a0, off, 64);
    a1 += __shfl_down(a1, off, 64);
    a2 += __shfl_down(a2, off, 64);
    a3 += __shfl_down(a3, off, 64);
  }
  if (lane == 0) {
    float l0 = a0 + bsel[0], l1 = a1 + bsel[1], l2 = a2 + bsel[2], l3 = a3 + bsel[3];
    float m = fmaxf(fmaxf(l0, l1), fmaxf(l2, l3));
    float e0 = __expf(l0 - m), e1 = __expf(l1 - m);
    float e2 = __expf(l2 - m), e3 = __expf(l3 - m);
    float inv = 1.0f / (e0 + e1 + e2 + e3);
    float* o = gwout + (size_t)t * 4;
    o[0] = e0 * inv; o[1] = e1 * inv; o[2] = e2 * inv; o[3] = e3 * inv;
  }
}

// ---------------- gemm_bt: 128x128 2-barrier kernel (round-0 proven) ----------------
// Used for gemm1 (K=512, short-K, epilogue-heavy): 32 KiB LDS -> 2 blocks/CU,
// so one block's gelu epilogue overlaps another block's MFMA.
template <int EPI>
__global__ __launch_bounds__(256, 2)
void gemm_bt(const unsigned short* __restrict__ A,
             const unsigned short* __restrict__ Bt,
             void* __restrict__ C, int K, int lda, int ldb, int ldc,
             const float* __restrict__ gw,
             const float* __restrict__ bias, int colOff, int accum) {
  __shared__ unsigned short lA[128 * 64];
  __shared__ unsigned short lB[128 * 64];
  const int tid = threadIdx.x;
  const int wave = tid >> 6;
  const int lane = tid & 63;
  const int rowA0 = blockIdx.x * 128;
  const int rowB0 = blockIdx.y * 128;

  f32x4 acc[4][4];
#pragma unroll
  for (int i = 0; i < 4; i++)
#pragma unroll
    for (int j = 0; j < 4; j++) acc[i][j] = (f32x4){0.f, 0.f, 0.f, 0.f};

  const int lrow = lane >> 3;
  const int lslot = lane & 7;
  const int gchunk = lslot ^ lrow;
  const int fr = lane & 15;
  const int quad = lane >> 4;
  const int wm = (wave >> 1) * 64;
  const int wn = (wave & 1) * 64;
  const int swz = fr & 7;

  for (int kt = 0; kt < K; kt += 64) {
#pragma unroll
    for (int c = 0; c < 4; c++) {
      int r = wave * 32 + c * 8 + lrow;
      const unsigned short* gp = A + (size_t)(rowA0 + r) * lda + kt + gchunk * 8;
      __builtin_amdgcn_global_load_lds(AS1U32(gp), AS3U32(lA + (wave * 32 + c * 8) * 64), 16, 0, 0);
    }
#pragma unroll
    for (int c = 0; c < 4; c++) {
      int r = wave * 32 + c * 8 + lrow;
      const unsigned short* gp = Bt + (size_t)(rowB0 + r) * ldb + kt + gchunk * 8;
      __builtin_amdgcn_global_load_lds(AS1U32(gp), AS3U32(lB + (wave * 32 + c * 8) * 64), 16, 0, 0);
    }
    __syncthreads();
#pragma unroll
    for (int ks = 0; ks < 2; ks++) {
      short8 af[4], bfr[4];
      const int c = ks * 4 + quad;
      const int slot = (c ^ swz) << 3;
#pragma unroll
      for (int i = 0; i < 4; i++)
        af[i] = *(const short8*)(lA + (wm + i * 16 + fr) * 64 + slot);
#pragma unroll
      for (int j = 0; j < 4; j++)
        bfr[j] = *(const short8*)(lB + (wn + j * 16 + fr) * 64 + slot);
#pragma unroll
      for (int i = 0; i < 4; i++)
#pragma unroll
        for (int j = 0; j < 4; j++)
          acc[i][j] = __builtin_amdgcn_mfma_f32_16x16x32_bf16(af[i], bfr[j], acc[i][j], 0, 0, 0);
    }
    __syncthreads();
  }

  if (EPI == 1) {
    unsigned short* Cb = (unsigned short*)C;
    const int kexp = (colOff + rowB0) >> 11;
#pragma unroll
    for (int i = 0; i < 4; i++) {
#pragma unroll
      for (int reg = 0; reg < 4; reg++) {
        int r = rowA0 + wm + i * 16 + quad * 4 + reg;
        float g = gw[(size_t)r * 4 + kexp];
#pragma unroll
        for (int j = 0; j < 4; j++) {
          int n = rowB0 + wn + j * 16 + fr;
          float v = acc[i][j][reg] + bias[colOff + n];
          Cb[(size_t)r * ldc + n] = f2bf(gelu_fast(v) * g);
        }
      }
    }
  } else {
    float* Cf = (float*)C;
#pragma unroll
    for (int i = 0; i < 4; i++) {
#pragma unroll
      for (int reg = 0; reg < 4; reg++) {
        int r = rowA0 + wm + i * 16 + quad * 4 + reg;
        size_t t4 = (size_t)r * 4;
        float g0 = gw[t4], g1 = gw[t4 + 1], g2 = gw[t4 + 2], g3 = gw[t4 + 3];
#pragma unroll
        for (int j = 0; j < 4; j++) {
          int n = rowB0 + wn + j * 16 + fr;
          size_t ci = (size_t)r * 512 + n;
          float v = acc[i][j][reg];
          if (accum) v += Cf[ci];
          else v += g0 * bias[n] + g1 * bias[512 + n] +
                    g2 * bias[1024 + n] + g3 * bias[1536 + n];
          Cf[ci] = v;
        }
      }
    }
  }
}

// ---------------- gemm8p: 8-phase double-buffered 256-row tile ----------------
// Used for gemm2 (long K = slabDF). NOTE: doswz stays 0 — with grid (64,4) the
// natural linear->XCD mapping (lin = bx + 64*by, 64 % 8 == 0) already places
// all 4 by-blocks sharing an A-row-slice on the SAME XCD L2. Round-2 A/B:
// swizzle broke that grouping -> FETCH_SIZE 98->283 MB and the counted-vmcnt
// pipeline stalled at L3/HBM latency (96.6 us, MfmaUtil 29%).

#define CFENCE asm volatile("" ::: "memory")
#define BAR    do { CFENCE; __builtin_amdgcn_s_barrier(); CFENCE; } while (0)
#define LGKM0  do { asm volatile("s_waitcnt lgkmcnt(0)" ::: "memory"); \
                    __builtin_amdgcn_sched_barrier(0); } while (0)
#define VMW(n) asm volatile("s_waitcnt vmcnt(" #n ")" ::: "memory")

#define LDA(abuf, mh)                                                       \
  do {                                                                      \
    _Pragma("unroll")                                                       \
    for (int m_ = 0; m_ < 4; m_++)                                          \
      _Pragma("unroll")                                                     \
      for (int ks_ = 0; ks_ < 2; ks_++)                                     \
        aF[m_][ks_] = *(const short8*)((abuf) +                             \
            (size_t)(wr * 128 + ((mh) * 4 + m_) * 16 + fr) * 64 +           \
            (((ks_ * 4 + quad) ^ swz) * 8));                                \
  } while (0)

#define LDB(bbuf, nh)                                                       \
  do {                                                                      \
    _Pragma("unroll")                                                       \
    for (int n_ = 0; n_ < NF2; n_++)                                        \
      _Pragma("unroll")                                                     \
      for (int ks_ = 0; ks_ < 2; ks_++)                                     \
        bF[nh][n_][ks_] = *(const short8*)((bbuf) +                         \
            (size_t)(wc * NWV + ((nh) * NF2 + n_) * 16 + fr) * 64 +         \
            (((ks_ * 4 + quad) ^ swz) * 8));                                \
  } while (0)

#define MM(mh, nh)                                                          \
  do {                                                                      \
    __builtin_amdgcn_s_setprio(1);                                          \
    _Pragma("unroll")                                                       \
    for (int m_ = 0; m_ < 4; m_++)                                          \
      _Pragma("unroll")                                                     \
      for (int n_ = 0; n_ < NF2; n_++)                                      \
        _Pragma("unroll")                                                   \
        for (int ks_ = 0; ks_ < 2; ks_++)                                   \
          acc[(mh) * 4 + m_][(nh) * NF2 + n_] =                             \
              __builtin_amdgcn_mfma_f32_16x16x32_bf16(                      \
                  aF[m_][ks_], bF[nh][n_][ks_],                             \
                  acc[(mh) * 4 + m_][(nh) * NF2 + n_], 0, 0, 0);            \
    __builtin_amdgcn_s_setprio(0);                                          \
  } while (0)

template <int NFREP, int EPI>
__global__ __launch_bounds__(512, 2)
void gemm8p(const unsigned short* __restrict__ A,
            const unsigned short* __restrict__ Bt,
            void* __restrict__ C, int K, int lda, int ldb, int ldc,
            const float* __restrict__ gw,
            const float* __restrict__ bias, int colOff, int accum, int doswz) {
  constexpr int BM = 256;
  constexpr int BN = NFREP * 64;
  constexpr int NWV = NFREP * 16;
  constexpr int NF2 = NFREP / 2;
  __shared__ unsigned short lds[2 * (BM * 64 + BN * 64)];

  const int tid = threadIdx.x;
  const int wave = tid >> 6, lane = tid & 63;
  const int lrow = lane >> 3, lslot = lane & 7, gch = lslot ^ lrow;
  const int wr = wave >> 2, wc = wave & 3;
  const int fr = lane & 15, quad = lane >> 4, swz = fr & 7;

  int bx = blockIdx.x, by = blockIdx.y;
  if (doswz) {   // bijective XCD swizzle; requires nwg % 8 == 0
    int nwg = gridDim.x * gridDim.y;
    int lin = by * gridDim.x + bx;
    int sw = (lin & 7) * (nwg >> 3) + (lin >> 3);
    bx = sw % gridDim.x; by = sw / gridDim.x;
  }
  const int rowA0 = bx * BM;
  const int rowB0 = by * BN;

  unsigned short* const A0 = lds;
  unsigned short* const B0 = lds + BM * 64;
  unsigned short* const A1 = lds + (BM * 64 + BN * 64);
  unsigned short* const B1 = A1 + BM * 64;

  auto stA = [&](unsigned short* ab, int h, int kt) {
#pragma unroll
    for (int j = 0; j < 2; j++) {
      int rg = h * 8 + wave + j * 16;
      const unsigned short* gp =
          A + (size_t)(rowA0 + rg * 8 + lrow) * lda + kt + gch * 8;
      __builtin_amdgcn_global_load_lds(AS1U32(gp), AS3U32(ab + rg * 512), 16, 0, 0);
    }
  };
  auto stB = [&](unsigned short* bb, int nh, int kt) {
    if constexpr (NFREP == 4) {
#pragma unroll
      for (int j = 0; j < 2; j++) {
        int idx = j * 8 + wave;
        int rg = (idx >> 2) * 8 + (idx & 3) + nh * 4;
        const unsigned short* gp =
            Bt + (size_t)(rowB0 + rg * 8 + lrow) * ldb + kt + gch * 8;
        __builtin_amdgcn_global_load_lds(AS1U32(gp), AS3U32(bb + rg * 512), 16, 0, 0);
      }
    } else {
      int rg = (wave >> 1) * 4 + (wave & 1) + nh * 2;
      const unsigned short* gp =
          Bt + (size_t)(rowB0 + rg * 8 + lrow) * ldb + kt + gch * 8;
      __builtin_amdgcn_global_load_lds(AS1U32(gp), AS3U32(bb + rg * 512), 16, 0, 0);
    }
  };

  f32x4 acc[8][NFREP];
#pragma unroll
  for (int i = 0; i < 8; i++)
#pragma unroll
    for (int j = 0; j < NFREP; j++) acc[i][j] = (f32x4){0.f, 0.f, 0.f, 0.f};

  short8 aF[4][2];
  short8 bF[2][NF2][2];

  // ---- prologue: stage tile0 -> buf0, tile1 -> buf1 ----
  stB(B0, 0, 0); stB(B0, 1, 0); stA(A0, 0, 0); stA(A0, 1, 0);
  stB(B1, 0, 64); stB(B1, 1, 64); stA(A1, 0, 64); stA(A1, 1, 64);
  if constexpr (NFREP == 4) VMW(8); else VMW(6);   // tile0 landed
  BAR;

  const int niter = K >> 7;   // K/128, two K-tiles per iteration
  for (int i = 0; i < niter - 1; i++) {
    const int kt = i * 128;
    // p0
    LDA(A0, 0); LDB(B0, 0);
    BAR; LGKM0; MM(0, 0); BAR;
    // p1
    LDB(B0, 1); stB(B0, 0, kt + 128);
    BAR; LGKM0; MM(0, 1); BAR;
    // p2
    LDA(A0, 1); stB(B0, 1, kt + 128);
    BAR; LGKM0; MM(1, 1); BAR;
    // p3
    stA(A0, 0, kt + 128);
    BAR; LGKM0; MM(1, 0);
    if constexpr (NFREP == 4) VMW(6); else VMW(4);  // buf1 current tile landed
    BAR;
    // p4
    LDA(A1, 0); LDB(B1, 0); stA(A0, 1, kt + 128);
    BAR; LGKM0; MM(0, 0); BAR;
    // p5
    LDB(B1, 1); stB(B1, 0, kt + 192);
    BAR; LGKM0; MM(0, 1); BAR;
    // p6
    LDA(A1, 1); stB(B1, 1, kt + 192);
    BAR; LGKM0; MM(1, 1); BAR;
    // p7
    stA(A1, 0, kt + 192); stA(A1, 1, kt + 192);
    BAR; LGKM0; MM(1, 0);
    if constexpr (NFREP == 4) VMW(8); else VMW(6);  // buf0 next tile landed
    BAR;
  }
  // ---- peeled last iteration ----
  LDA(A0, 0); LDB(B0, 0); BAR; LGKM0; MM(0, 0); BAR;
  LDB(B0, 1);             BAR; LGKM0; MM(0, 1); BAR;
  LDA(A0, 1);             BAR; LGKM0; MM(1, 1); BAR;
                          BAR; LGKM0; MM(1, 0); VMW(0); BAR;
  LDA(A1, 0); LDB(B1, 0); BAR; LGKM0; MM(0, 0); BAR;
  LDB(B1, 1);             BAR; LGKM0; MM(0, 1); BAR;
  LDA(A1, 1);             BAR; LGKM0; MM(1, 1); BAR;
                          BAR; LGKM0; MM(1, 0);

  // ---- epilogue ----
  if (EPI == 1) {
    unsigned short* Cb = (unsigned short*)C;
    const int kexp = (colOff + rowB0) >> 11;
#pragma unroll
    for (int m = 0; m < 8; m++) {
#pragma unroll
      for (int reg = 0; reg < 4; reg++) {
        int r = rowA0 + wr * 128 + m * 16 + quad * 4 + reg;
        float g = gw[(size_t)r * 4 + kexp];
#pragma unroll
        for (int n = 0; n < NFREP; n++) {
          int col = rowB0 + wc * NWV + n * 16 + fr;
          float v = acc[m][n][reg] + bias[colOff + col];
          Cb[(size_t)r * ldc + col] = f2bf(gelu_fast(v) * g);
        }
      }
    }
  } else {
    float* Cf = (float*)C;
#pragma unroll
    for (int m = 0; m < 8; m++) {
#pragma unroll
      for (int reg = 0; reg < 4; reg++) {
        int r = rowA0 + wr * 128 + m * 16 + quad * 4 + reg;
        size_t t4 = (size_t)r * 4;
        float g0 = gw[t4], g1 = gw[t4 + 1], g2 = gw[t4 + 2], g3 = gw[t4 + 3];
#pragma unroll
        for (int n = 0; n < NFREP; n++) {
          int col = rowB0 + wc * NWV + n * 16 + fr;
          size_t ci = (size_t)r * 512 + col;
          float v = acc[m][n][reg];
          if (accum) v += Cf[ci];
          else v += g0 * bias[col] + g1 * bias[512 + col] +
                    g2 * bias[1024 + col] + g3 * bias[1536 + col];
          Cf[ci] = v;
        }
      }
    }
  }
}

#undef LDA
#undef LDB
#undef MM

// ---------------- launch ----------------

extern "C" void kernel_launch(void* const* d_in, const int* in_sizes, int n_in,
                              void* d_out, int out_size, void* d_ws, size_t ws_size,
                              hipStream_t stream) {
  (void)in_sizes; (void)n_in; (void)out_size;
  const float* x      = (const float*)d_in[0];
  const float* gate_w = (const float*)d_in[1];
  const float* gate_b = (const float*)d_in[2];
  const float* w1     = (const float*)d_in[3];
  const float* b1     = (const float*)d_in[4];
  const float* w2     = (const float*)d_in[5];
  const float* b2     = (const float*)d_in[6];

  char* ws = (char*)d_ws;
  int*            idx   = (int*)(ws + 0);                //  16 B
  float*          gw    = (float*)(ws + 4096);           // 256 KB  [T,4]
  float*          b1cat = (float*)(ws + 266240);         //  32 KB
  float*          b2sel = (float*)(ws + 299008);         //   8 KB
  float*          kpart = (float*)(ws + 307200);         // 512 KB  [256,512]
  unsigned short* xbf   = (unsigned short*)(ws + 831488);      // 16.8 MB [T,512]
  unsigned short* w1t   = (unsigned short*)(ws + 17608704);    //  8.4 MB [8192,512]
  unsigned short* w2t   = (unsigned short*)(ws + 25997312);    //  8.4 MB [512,8192]
  unsigned short* hbuf  = (unsigned short*)(ws + 34385920);    // h' slab
  const size_t HBUF_OFF = 34385920;

  size_t avail = ws_size > HBUF_OFF ? ws_size - HBUF_OFF : 0;
  int nslab = 1;
  while (nslab < 16 && (size_t)16384 * (8192 / nslab) * 2 > avail) nslab <<= 1;
  const int slabDF = 8192 / nslab;

  reduce_part<<<256, 512, 0, stream>>>(x, kpart);
  gate_all<<<1, 1024, 0, stream>>>(kpart, gate_w, gate_b, b1, b2, idx, b1cat, b2sel);
  transpose_all<<<dim3(8, 32, 8), 256, 0, stream>>>(w1, w2, w1t, w2t, idx);
  gate_softmax_xconv<<<4096, 256, 0, stream>>>(x, gate_w, gate_b, idx, gw, xbf);

  for (int s = 0; s < nslab; s++) {
    const int c0 = s * slabDF;
    // gemm1 (short K=512, gelu epilogue): proven 128^2 2-barrier structure,
    // 2 blocks/CU so epilogue overlaps other blocks' MFMA.
    gemm_bt<1><<<dim3(128, slabDF / 128), 256, 0, stream>>>(
        xbf, w1t + (size_t)c0 * 512, hbuf,
        /*K=*/512, /*lda=*/512, /*ldb=*/512, /*ldc=*/slabDF,
        gw, b1cat, c0, 0);
    // gemm2 (long K=slabDF): 8-phase counted-vmcnt structure, NO swizzle
    // (natural mapping XCD-groups the A-sharing blocks; see comment above).
    gemm8p<2, 2><<<dim3(64, 4), 512, 0, stream>>>(
        hbuf, w2t + c0, (float*)d_out,
        /*K=*/slabDF, /*lda=*/slabDF, /*ldb=*/8192, /*ldc=*/512,
        gw, b2sel, 0, s > 0, 0);
  }
}

// Round 4
// 530.732 us; speedup vs baseline: 1.0538x; 1.0063x over previous
//
#include <hip/hip_runtime.h>
#include <hip/hip_bf16.h>
#include <cstdint>
#include <cstddef>

typedef __attribute__((ext_vector_type(8))) short short8;
typedef __attribute__((ext_vector_type(4))) float f32x4;

#define AS1U32(p) ((const __attribute__((address_space(1))) uint32_t*)(p))
#define AS3U32(p) ((__attribute__((address_space(3))) uint32_t*)(p))

__device__ __forceinline__ unsigned short f2bf(float v) {
  union { float f; uint32_t u; } a; a.f = v;
  uint32_t u = a.u;
  u += 0x7FFFu + ((u >> 16) & 1u);   // round-to-nearest-even
  return (unsigned short)(u >> 16);
}

// gelu(x) = x * sigmoid(2u), u = sqrt(2/pi)(x + 0.044715 x^3)
__device__ __forceinline__ float gelu_fast(float x) {
  const float c0 = 0.7978845608028654f;
  const float c1 = 0.044715f;
  float u = c0 * (x + c1 * x * x * x);
  return x * __builtin_amdgcn_rcpf(1.0f + __expf(-2.0f * u));
}

// ---------------- prologue kernels (unchanged) ----------------

__global__ __launch_bounds__(512)
void reduce_part(const float* __restrict__ x, float* __restrict__ kpart) {
  const int d = threadIdx.x;
  const int b = blockIdx.x;
  float s = 0.f;
#pragma unroll 4
  for (int i = 0; i < 64; i++)
    s += x[((size_t)b * 64 + i) * 512 + d];
  kpart[(size_t)b * 512 + d] = s;
}

__global__ __launch_bounds__(1024)
void gate_all(const float* __restrict__ kpart,
              const float* __restrict__ gate_w,
              const float* __restrict__ gate_b,
              const float* __restrict__ b1, const float* __restrict__ b2,
              int* __restrict__ idxout,
              float* __restrict__ b1cat, float* __restrict__ b2sel) {
  __shared__ float ksum2[2][512];
  __shared__ float coarse[16];
  __shared__ int idxl[4];
  const int t = threadIdx.x;
  {
    const int d = t & 511, h = t >> 9;
    float s = 0.f;
    for (int p = h * 128; p < h * 128 + 128; p++) s += kpart[(size_t)p * 512 + d];
    ksum2[h][d] = s;
  }
  __syncthreads();
  {
    const int wave = t >> 6, lane = t & 63;
    const int d0 = lane * 8;
    float s = 0.f;
#pragma unroll
    for (int j = 0; j < 8; j++)
      s += gate_w[wave * 512 + d0 + j] * (ksum2[0][d0 + j] + ksum2[1][d0 + j]);
#pragma unroll
    for (int off = 32; off >= 1; off >>= 1) s += __shfl_down(s, off, 64);
    if (lane == 0) coarse[wave] = s + gate_b[wave];
  }
  __syncthreads();
  if (t == 0) {
    unsigned taken = 0;
    for (int r = 0; r < 4; r++) {
      float best = -3.4e38f; int bi = 0;
      for (int e = 0; e < 16; e++)
        if (!((taken >> e) & 1u) && coarse[e] > best) { best = coarse[e]; bi = e; }
      taken |= 1u << bi;
      idxl[r] = bi; idxout[r] = bi;
    }
  }
  __syncthreads();
  for (int i = t; i < 8192; i += 1024)
    b1cat[i] = b1[(size_t)idxl[i >> 11] * 2048 + (i & 2047)];
  for (int i = t; i < 2048; i += 1024)
    b2sel[i] = b2[(size_t)idxl[i >> 9] * 512 + (i & 511)];
}

__global__ __launch_bounds__(256)
void transpose_all(const float* __restrict__ w1, const float* __restrict__ w2,
                   unsigned short* __restrict__ w1t, unsigned short* __restrict__ w2t,
                   const int* __restrict__ idx) {
  __shared__ float tl[64][65];
  const int tid = threadIdx.x;
  const int ty = tid >> 6, tx = tid & 63;
  const int z = blockIdx.z;
  const float* src; unsigned short* dbase; int C, dstLd, r0, c0;
  if (z < 4) {
    src = w1 + (size_t)idx[z] * 512 * 2048;
    dbase = w1t + (size_t)z * 2048 * 512;
    C = 2048; dstLd = 512;
    r0 = blockIdx.x * 64; c0 = blockIdx.y * 64;
  } else {
    src = w2 + (size_t)idx[z - 4] * 2048 * 512;
    dbase = w2t + (size_t)(z - 4) * 2048;
    C = 512; dstLd = 8192;
    r0 = blockIdx.y * 64; c0 = blockIdx.x * 64;
  }
#pragma unroll
  for (int i = 0; i < 16; i++) {
    int r = ty * 16 + i;
    tl[r][tx] = src[(size_t)(r0 + r) * C + c0 + tx];
  }
  __syncthreads();
#pragma unroll
  for (int i = 0; i < 16; i++) {
    int rr = ty * 16 + i;
    dbase[(size_t)(c0 + rr) * dstLd + r0 + tx] = f2bf(tl[tx][rr]);
  }
}

__global__ __launch_bounds__(256)
void gate_softmax_xconv(const float* __restrict__ x,
                        const float* __restrict__ gate_w,
                        const float* __restrict__ gate_b,
                        const int* __restrict__ idx,
                        float* __restrict__ gwout,
                        unsigned short* __restrict__ xbf) {
  __shared__ float wsel[4][512];
  __shared__ float bsel[4];
  const int tid = threadIdx.x;
  for (int i = tid; i < 2048; i += 256) {
    int k = i >> 9;
    wsel[k][i & 511] = gate_w[(size_t)idx[k] * 512 + (i & 511)];
  }
  if (tid < 4) bsel[tid] = gate_b[idx[tid]];
  __syncthreads();
  const int wave = tid >> 6, lane = tid & 63;
  const int t = blockIdx.x * 4 + wave;
  const float* xr = x + (size_t)t * 512 + lane * 8;
  float4 v0 = ((const float4*)xr)[0];
  float4 v1 = ((const float4*)xr)[1];
  float vals[8] = {v0.x, v0.y, v0.z, v0.w, v1.x, v1.y, v1.z, v1.w};
  short8 pk;
#pragma unroll
  for (int j = 0; j < 8; j++) pk[j] = (short)f2bf(vals[j]);
  *(short8*)(xbf + (size_t)t * 512 + lane * 8) = pk;
  float a0 = 0.f, a1 = 0.f, a2 = 0.f, a3 = 0.f;
  const int dbase = lane * 8;
#pragma unroll
  for (int j = 0; j < 8; j++) {
    float xv = vals[j];
    a0 += xv * wsel[0][dbase + j];
    a1 += xv * wsel[1][dbase + j];
    a2 += xv * wsel[2][dbase + j];
    a3 += xv * wsel[3][dbase + j];
  }
#pragma unroll
  for (int off = 32; off >= 1; off >>= 1) {
    a0 += __shfl_down(a0, off, 64);
    a1 += __shfl_down(a1, off, 64);
    a2 += __shfl_down(a2, off, 64);
    a3 += __shfl_down(a3, off, 64);
  }
  if (lane == 0) {
    float l0 = a0 + bsel[0], l1 = a1 + bsel[1], l2 = a2 + bsel[2], l3 = a3 + bsel[3];
    float m = fmaxf(fmaxf(l0, l1), fmaxf(l2, l3));
    float e0 = __expf(l0 - m), e1 = __expf(l1 - m);
    float e2 = __expf(l2 - m), e3 = __expf(l3 - m);
    float inv = 1.0f / (e0 + e1 + e2 + e3);
    float* o = gwout + (size_t)t * 4;
    o[0] = e0 * inv; o[1] = e1 * inv; o[2] = e2 * inv; o[3] = e3 * inv;
  }
}

// ---------------- gemm_bt: 128x128 2-barrier kernel (round-0 proven) ----------------
// Used for gemm1 (K=512, short-K, epilogue-heavy): 32 KiB LDS -> 2 blocks/CU,
// so one block's gelu epilogue overlaps another block's MFMA.
template <int EPI>
__global__ __launch_bounds__(256, 2)
void gemm_bt(const unsigned short* __restrict__ A,
             const unsigned short* __restrict__ Bt,
             void* __restrict__ C, int K, int lda, int ldb, int ldc,
             const float* __restrict__ gw,
             const float* __restrict__ bias, int colOff, int accum) {
  __shared__ unsigned short lA[128 * 64];
  __shared__ unsigned short lB[128 * 64];
  const int tid = threadIdx.x;
  const int wave = tid >> 6;
  const int lane = tid & 63;
  const int rowA0 = blockIdx.x * 128;
  const int rowB0 = blockIdx.y * 128;

  f32x4 acc[4][4];
#pragma unroll
  for (int i = 0; i < 4; i++)
#pragma unroll
    for (int j = 0; j < 4; j++) acc[i][j] = (f32x4){0.f, 0.f, 0.f, 0.f};

  const int lrow = lane >> 3;
  const int lslot = lane & 7;
  const int gchunk = lslot ^ lrow;
  const int fr = lane & 15;
  const int quad = lane >> 4;
  const int wm = (wave >> 1) * 64;
  const int wn = (wave & 1) * 64;
  const int swz = fr & 7;

  for (int kt = 0; kt < K; kt += 64) {
#pragma unroll
    for (int c = 0; c < 4; c++) {
      int r = wave * 32 + c * 8 + lrow;
      const unsigned short* gp = A + (size_t)(rowA0 + r) * lda + kt + gchunk * 8;
      __builtin_amdgcn_global_load_lds(AS1U32(gp), AS3U32(lA + (wave * 32 + c * 8) * 64), 16, 0, 0);
    }
#pragma unroll
    for (int c = 0; c < 4; c++) {
      int r = wave * 32 + c * 8 + lrow;
      const unsigned short* gp = Bt + (size_t)(rowB0 + r) * ldb + kt + gchunk * 8;
      __builtin_amdgcn_global_load_lds(AS1U32(gp), AS3U32(lB + (wave * 32 + c * 8) * 64), 16, 0, 0);
    }
    __syncthreads();
#pragma unroll
    for (int ks = 0; ks < 2; ks++) {
      short8 af[4], bfr[4];
      const int c = ks * 4 + quad;
      const int slot = (c ^ swz) << 3;
#pragma unroll
      for (int i = 0; i < 4; i++)
        af[i] = *(const short8*)(lA + (wm + i * 16 + fr) * 64 + slot);
#pragma unroll
      for (int j = 0; j < 4; j++)
        bfr[j] = *(const short8*)(lB + (wn + j * 16 + fr) * 64 + slot);
#pragma unroll
      for (int i = 0; i < 4; i++)
#pragma unroll
        for (int j = 0; j < 4; j++)
          acc[i][j] = __builtin_amdgcn_mfma_f32_16x16x32_bf16(af[i], bfr[j], acc[i][j], 0, 0, 0);
    }
    __syncthreads();
  }

  if (EPI == 1) {
    unsigned short* Cb = (unsigned short*)C;
    const int kexp = (colOff + rowB0) >> 11;
#pragma unroll
    for (int i = 0; i < 4; i++) {
#pragma unroll
      for (int reg = 0; reg < 4; reg++) {
        int r = rowA0 + wm + i * 16 + quad * 4 + reg;
        float g = gw[(size_t)r * 4 + kexp];
#pragma unroll
        for (int j = 0; j < 4; j++) {
          int n = rowB0 + wn + j * 16 + fr;
          float v = acc[i][j][reg] + bias[colOff + n];
          Cb[(size_t)r * ldc + n] = f2bf(gelu_fast(v) * g);
        }
      }
    }
  } else {
    float* Cf = (float*)C;
#pragma unroll
    for (int i = 0; i < 4; i++) {
#pragma unroll
      for (int reg = 0; reg < 4; reg++) {
        int r = rowA0 + wm + i * 16 + quad * 4 + reg;
        size_t t4 = (size_t)r * 4;
        float g0 = gw[t4], g1 = gw[t4 + 1], g2 = gw[t4 + 2], g3 = gw[t4 + 3];
#pragma unroll
        for (int j = 0; j < 4; j++) {
          int n = rowB0 + wn + j * 16 + fr;
          size_t ci = (size_t)r * 512 + n;
          float v = acc[i][j][reg];
          if (accum) v += Cf[ci];
          else v += g0 * bias[n] + g1 * bias[512 + n] +
                    g2 * bias[1024 + n] + g3 * bias[1536 + n];
          Cf[ci] = v;
        }
      }
    }
  }
}

// ---------------- gemm4p: 4-phase double-buffered 256x128 tile (gemm2) ----------------
// Round-3 diagnosis: at BN=128 the 8-phase schedule had only 8 MFMA (~307 cy/CU)
// between each barrier-pair -> per-phase fixed costs (8-wave barrier sync, lgkm
// drain, lockstep ds_reads) were ~50% overhead -> MfmaUtil 30%. This schedule
// doubles MFMA per phase (16) and cuts barriers 16 -> 6 per 128-K iteration.
//   P0: ds_read ALL buf0 frags (20x b128) | BAR | lgkm0 | MFMA m-half0 | BAR
//   P1: stage next buf0 tile (6 loads)          | MFMA m-half1 | vmcnt(6) | BAR
//   P2: ds_read ALL buf1 frags              | BAR | lgkm0 | MFMA m-half0 | BAR
//   P3: stage next buf1 tile (6 loads)          | MFMA m-half1 | vmcnt(6) | BAR
// Hazards: stage into region R only in a phase after R's last ds_read phase's
// trailing barrier (buf0 fully read in P0 -> stage P1; buf1 read P2 -> stage P3).
// vmcnt: 12 outstanding at each wait; oldest 6 are the tile needed 3 phases
// later (~2000cy slack > 900cy HBM latency). NO XCD swizzle (round-2 lesson:
// natural lin = bx + 64*by groups the 4 A-sharing blocks on one XCD L2).

#define CFENCE asm volatile("" ::: "memory")
#define BAR    do { CFENCE; __builtin_amdgcn_s_barrier(); CFENCE; } while (0)
#define LGKM0  do { asm volatile("s_waitcnt lgkmcnt(0)" ::: "memory"); \
                    __builtin_amdgcn_sched_barrier(0); } while (0)
#define SCHEDB __builtin_amdgcn_sched_barrier(0)
#define VMW(n) asm volatile("s_waitcnt vmcnt(" #n ")" ::: "memory")

#define LDALL(abuf, bbuf)                                                   \
  do {                                                                      \
    _Pragma("unroll")                                                       \
    for (int m_ = 0; m_ < 8; m_++)                                          \
      _Pragma("unroll")                                                     \
      for (int ks_ = 0; ks_ < 2; ks_++)                                     \
        aF[m_][ks_] = *(const short8*)((abuf) +                             \
            (size_t)(wr * 128 + m_ * 16 + fr) * 64 +                        \
            (((ks_ * 4 + quad) ^ swz) * 8));                                \
    _Pragma("unroll")                                                       \
    for (int nh_ = 0; nh_ < 2; nh_++)                                       \
      _Pragma("unroll")                                                     \
      for (int ks_ = 0; ks_ < 2; ks_++)                                     \
        bF[nh_][ks_] = *(const short8*)((bbuf) +                            \
            (size_t)(wc * 32 + nh_ * 16 + fr) * 64 +                        \
            (((ks_ * 4 + quad) ^ swz) * 8));                                \
  } while (0)

#define MMH(h)                                                              \
  do {                                                                      \
    __builtin_amdgcn_s_setprio(1);                                          \
    _Pragma("unroll")                                                       \
    for (int m_ = 0; m_ < 4; m_++)                                          \
      _Pragma("unroll")                                                     \
      for (int nh_ = 0; nh_ < 2; nh_++)                                     \
        _Pragma("unroll")                                                   \
        for (int ks_ = 0; ks_ < 2; ks_++)                                   \
          acc[(h) * 4 + m_][nh_] =                                          \
              __builtin_amdgcn_mfma_f32_16x16x32_bf16(                      \
                  aF[(h) * 4 + m_][ks_], bF[nh_][ks_],                      \
                  acc[(h) * 4 + m_][nh_], 0, 0, 0);                         \
    __builtin_amdgcn_s_setprio(0);                                          \
  } while (0)

__global__ __launch_bounds__(512, 2)
void gemm4p(const unsigned short* __restrict__ A,
            const unsigned short* __restrict__ Bt,
            float* __restrict__ Cf, int K, int lda, int ldb,
            const float* __restrict__ gw,
            const float* __restrict__ bias, int accum) {
  constexpr int BM = 256;
  constexpr int BN = 128;
  __shared__ unsigned short lds[2 * (BM * 64 + BN * 64)];

  const int tid = threadIdx.x;
  const int wave = tid >> 6, lane = tid & 63;
  const int lrow = lane >> 3, lslot = lane & 7, gch = lslot ^ lrow;
  const int wr = wave >> 2, wc = wave & 3;
  const int fr = lane & 15, quad = lane >> 4, swz = fr & 7;

  const int rowA0 = blockIdx.x * BM;
  const int rowB0 = blockIdx.y * BN;

  unsigned short* const A0 = lds;
  unsigned short* const B0 = lds + BM * 64;
  unsigned short* const A1 = lds + (BM * 64 + BN * 64);
  unsigned short* const B1 = A1 + BM * 64;

  // stage one A m-half (2 loads/thread): rows h*64 .. h*64+... (rg covers 256 rows over h=0,1)
  auto stA = [&](unsigned short* ab, int h, int kt) {
#pragma unroll
    for (int j = 0; j < 2; j++) {
      int rg = h * 8 + wave + j * 16;
      const unsigned short* gp =
          A + (size_t)(rowA0 + rg * 8 + lrow) * lda + kt + gch * 8;
      __builtin_amdgcn_global_load_lds(AS1U32(gp), AS3U32(ab + rg * 512), 16, 0, 0);
    }
  };
  // stage one B n-half (1 load/thread)
  auto stB = [&](unsigned short* bb, int nh, int kt) {
    int rg = (wave >> 1) * 4 + (wave & 1) + nh * 2;
    const unsigned short* gp =
        Bt + (size_t)(rowB0 + rg * 8 + lrow) * ldb + kt + gch * 8;
    __builtin_amdgcn_global_load_lds(AS1U32(gp), AS3U32(bb + rg * 512), 16, 0, 0);
  };
  // stage a full tile into one buffer: 6 loads/thread
  auto stTile = [&](unsigned short* ab, unsigned short* bb, int kt) {
    stB(bb, 0, kt); stB(bb, 1, kt);
    stA(ab, 0, kt); stA(ab, 1, kt);
  };

  f32x4 acc[8][2];
#pragma unroll
  for (int i = 0; i < 8; i++)
#pragma unroll
    for (int j = 0; j < 2; j++) acc[i][j] = (f32x4){0.f, 0.f, 0.f, 0.f};

  short8 aF[8][2];
  short8 bF[2][2];

  // ---- prologue: tile0 -> buf0, tile1 -> buf1 (6 + 6 loads/thread) ----
  stTile(A0, B0, 0);
  stTile(A1, B1, 64);
  VMW(6);            // tile0 landed (6 newest = tile1 may be in flight)
  BAR;

  const int niter = K >> 7;   // two K-tiles (64 each) per iteration
  for (int i = 0; i < niter - 1; i++) {
    const int kt = i * 128;
    // P0: read all buf0 fragments, compute m-half 0
    LDALL(A0, B0);
    BAR; LGKM0; MMH(0); BAR;
    // P1: stage next buf0 tile, compute m-half 1
    stTile(A0, B0, kt + 128); SCHEDB;
    MMH(1); VMW(6); BAR;
    // P2: read all buf1 fragments, compute m-half 0
    LDALL(A1, B1);
    BAR; LGKM0; MMH(0); BAR;
    // P3: stage next buf1 tile, compute m-half 1
    stTile(A1, B1, kt + 192); SCHEDB;
    MMH(1); VMW(6); BAR;
  }
  // ---- peeled last iteration (no staging) ----
  LDALL(A0, B0);
  BAR; LGKM0; MMH(0); BAR;
  MMH(1); VMW(0); BAR;
  LDALL(A1, B1);
  BAR; LGKM0; MMH(0); BAR;
  MMH(1);

  // ---- epilogue (f32 out, bias-combine on first slab, accumulate after) ----
#pragma unroll
  for (int m = 0; m < 8; m++) {
#pragma unroll
    for (int reg = 0; reg < 4; reg++) {
      int r = rowA0 + wr * 128 + m * 16 + quad * 4 + reg;
      size_t t4 = (size_t)r * 4;
      float g0 = gw[t4], g1 = gw[t4 + 1], g2 = gw[t4 + 2], g3 = gw[t4 + 3];
#pragma unroll
      for (int n = 0; n < 2; n++) {
        int col = rowB0 + wc * 32 + n * 16 + fr;
        size_t ci = (size_t)r * 512 + col;
        float v = acc[m][n][reg];
        if (accum) v += Cf[ci];
        else v += g0 * bias[col] + g1 * bias[512 + col] +
                  g2 * bias[1024 + col] + g3 * bias[1536 + col];
        Cf[ci] = v;
      }
    }
  }
}

#undef LDALL
#undef MMH

// ---------------- launch ----------------

extern "C" void kernel_launch(void* const* d_in, const int* in_sizes, int n_in,
                              void* d_out, int out_size, void* d_ws, size_t ws_size,
                              hipStream_t stream) {
  (void)in_sizes; (void)n_in; (void)out_size;
  const float* x      = (const float*)d_in[0];
  const float* gate_w = (const float*)d_in[1];
  const float* gate_b = (const float*)d_in[2];
  const float* w1     = (const float*)d_in[3];
  const float* b1     = (const float*)d_in[4];
  const float* w2     = (const float*)d_in[5];
  const float* b2     = (const float*)d_in[6];

  char* ws = (char*)d_ws;
  int*            idx   = (int*)(ws + 0);                //  16 B
  float*          gw    = (float*)(ws + 4096);           // 256 KB  [T,4]
  float*          b1cat = (float*)(ws + 266240);         //  32 KB
  float*          b2sel = (float*)(ws + 299008);         //   8 KB
  float*          kpart = (float*)(ws + 307200);         // 512 KB  [256,512]
  unsigned short* xbf   = (unsigned short*)(ws + 831488);      // 16.8 MB [T,512]
  unsigned short* w1t   = (unsigned short*)(ws + 17608704);    //  8.4 MB [8192,512]
  unsigned short* w2t   = (unsigned short*)(ws + 25997312);    //  8.4 MB [512,8192]
  unsigned short* hbuf  = (unsigned short*)(ws + 34385920);    // h' slab
  const size_t HBUF_OFF = 34385920;

  size_t avail = ws_size > HBUF_OFF ? ws_size - HBUF_OFF : 0;
  int nslab = 1;
  while (nslab < 16 && (size_t)16384 * (8192 / nslab) * 2 > avail) nslab <<= 1;
  const int slabDF = 8192 / nslab;

  reduce_part<<<256, 512, 0, stream>>>(x, kpart);
  gate_all<<<1, 1024, 0, stream>>>(kpart, gate_w, gate_b, b1, b2, idx, b1cat, b2sel);
  transpose_all<<<dim3(8, 32, 8), 256, 0, stream>>>(w1, w2, w1t, w2t, idx);
  gate_softmax_xconv<<<4096, 256, 0, stream>>>(x, gate_w, gate_b, idx, gw, xbf);

  for (int s = 0; s < nslab; s++) {
    const int c0 = s * slabDF;
    // gemm1 (short K=512, gelu epilogue): proven 128^2 2-barrier structure,
    // 2 blocks/CU so epilogue overlaps other blocks' MFMA.
    gemm_bt<1><<<dim3(128, slabDF / 128), 256, 0, stream>>>(
        xbf, w1t + (size_t)c0 * 512, hbuf,
        /*K=*/512, /*lda=*/512, /*ldb=*/512, /*ldc=*/slabDF,
        gw, b1cat, c0, 0);
    // gemm2 (long K=slabDF): 4-phase counted-vmcnt structure, no swizzle.
    gemm4p<<<dim3(64, 4), 512, 0, stream>>>(
        hbuf, w2t + c0, (float*)d_out,
        /*K=*/slabDF, /*lda=*/slabDF, /*ldb=*/8192,
        gw, b2sel, s > 0);
  }
}

// Round 5
// 502.092 us; speedup vs baseline: 1.1139x; 1.0570x over previous
//
#include <hip/hip_runtime.h>
#include <hip/hip_bf16.h>
#include <cstdint>
#include <cstddef>

typedef __attribute__((ext_vector_type(8))) short short8;
typedef __attribute__((ext_vector_type(4))) float f32x4;

#define AS1U32(p) ((const __attribute__((address_space(1))) uint32_t*)(p))
#define AS3U32(p) ((__attribute__((address_space(3))) uint32_t*)(p))

__device__ __forceinline__ unsigned short f2bf(float v) {
  union { float f; uint32_t u; } a; a.f = v;
  uint32_t u = a.u;
  u += 0x7FFFu + ((u >> 16) & 1u);   // round-to-nearest-even
  return (unsigned short)(u >> 16);
}

// gelu(x) = x * sigmoid(2u), u = sqrt(2/pi)(x + 0.044715 x^3)
// exp2-folded: sig = 1/(1+exp2(x*(A + B*x^2))), A = -2*c0*log2e, B = A*c1
__device__ __forceinline__ float gelu_fast(float x) {
  const float A = -2.302118142f;      // -2*0.7978845608*1.4426950409
  const float B = -0.102943494f;      // A*0.044715
  float x2 = x * x;
  float t = x * __builtin_fmaf(B, x2, A);
  float e = __builtin_amdgcn_exp2f(t);
  return x * __builtin_amdgcn_rcpf(1.0f + e);
}

// ---------------- prologue kernels (unchanged) ----------------

__global__ __launch_bounds__(512)
void reduce_part(const float* __restrict__ x, float* __restrict__ kpart) {
  const int d = threadIdx.x;
  const int b = blockIdx.x;
  float s = 0.f;
#pragma unroll 4
  for (int i = 0; i < 64; i++)
    s += x[((size_t)b * 64 + i) * 512 + d];
  kpart[(size_t)b * 512 + d] = s;
}

__global__ __launch_bounds__(1024)
void gate_all(const float* __restrict__ kpart,
              const float* __restrict__ gate_w,
              const float* __restrict__ gate_b,
              const float* __restrict__ b1, const float* __restrict__ b2,
              int* __restrict__ idxout,
              float* __restrict__ b1cat, float* __restrict__ b2sel) {
  __shared__ float ksum2[2][512];
  __shared__ float coarse[16];
  __shared__ int idxl[4];
  const int t = threadIdx.x;
  {
    const int d = t & 511, h = t >> 9;
    float s = 0.f;
    for (int p = h * 128; p < h * 128 + 128; p++) s += kpart[(size_t)p * 512 + d];
    ksum2[h][d] = s;
  }
  __syncthreads();
  {
    const int wave = t >> 6, lane = t & 63;
    const int d0 = lane * 8;
    float s = 0.f;
#pragma unroll
    for (int j = 0; j < 8; j++)
      s += gate_w[wave * 512 + d0 + j] * (ksum2[0][d0 + j] + ksum2[1][d0 + j]);
#pragma unroll
    for (int off = 32; off >= 1; off >>= 1) s += __shfl_down(s, off, 64);
    if (lane == 0) coarse[wave] = s + gate_b[wave];
  }
  __syncthreads();
  if (t == 0) {
    unsigned taken = 0;
    for (int r = 0; r < 4; r++) {
      float best = -3.4e38f; int bi = 0;
      for (int e = 0; e < 16; e++)
        if (!((taken >> e) & 1u) && coarse[e] > best) { best = coarse[e]; bi = e; }
      taken |= 1u << bi;
      idxl[r] = bi; idxout[r] = bi;
    }
  }
  __syncthreads();
  for (int i = t; i < 8192; i += 1024)
    b1cat[i] = b1[(size_t)idxl[i >> 11] * 2048 + (i & 2047)];
  for (int i = t; i < 2048; i += 1024)
    b2sel[i] = b2[(size_t)idxl[i >> 9] * 512 + (i & 511)];
}

__global__ __launch_bounds__(256)
void transpose_all(const float* __restrict__ w1, const float* __restrict__ w2,
                   unsigned short* __restrict__ w1t, unsigned short* __restrict__ w2t,
                   const int* __restrict__ idx) {
  __shared__ float tl[64][65];
  const int tid = threadIdx.x;
  const int ty = tid >> 6, tx = tid & 63;
  const int z = blockIdx.z;
  const float* src; unsigned short* dbase; int C, dstLd, r0, c0;
  if (z < 4) {
    src = w1 + (size_t)idx[z] * 512 * 2048;
    dbase = w1t + (size_t)z * 2048 * 512;
    C = 2048; dstLd = 512;
    r0 = blockIdx.x * 64; c0 = blockIdx.y * 64;
  } else {
    src = w2 + (size_t)idx[z - 4] * 2048 * 512;
    dbase = w2t + (size_t)(z - 4) * 2048;
    C = 512; dstLd = 8192;
    r0 = blockIdx.y * 64; c0 = blockIdx.x * 64;
  }
#pragma unroll
  for (int i = 0; i < 16; i++) {
    int r = ty * 16 + i;
    tl[r][tx] = src[(size_t)(r0 + r) * C + c0 + tx];
  }
  __syncthreads();
#pragma unroll
  for (int i = 0; i < 16; i++) {
    int rr = ty * 16 + i;
    dbase[(size_t)(c0 + rr) * dstLd + r0 + tx] = f2bf(tl[tx][rr]);
  }
}

__global__ __launch_bounds__(256)
void gate_softmax_xconv(const float* __restrict__ x,
                        const float* __restrict__ gate_w,
                        const float* __restrict__ gate_b,
                        const int* __restrict__ idx,
                        float* __restrict__ gwout,
                        unsigned short* __restrict__ xbf) {
  __shared__ float wsel[4][512];
  __shared__ float bsel[4];
  const int tid = threadIdx.x;
  for (int i = tid; i < 2048; i += 256) {
    int k = i >> 9;
    wsel[k][i & 511] = gate_w[(size_t)idx[k] * 512 + (i & 511)];
  }
  if (tid < 4) bsel[tid] = gate_b[idx[tid]];
  __syncthreads();
  const int wave = tid >> 6, lane = tid & 63;
  const int t = blockIdx.x * 4 + wave;
  const float* xr = x + (size_t)t * 512 + lane * 8;
  float4 v0 = ((const float4*)xr)[0];
  float4 v1 = ((const float4*)xr)[1];
  float vals[8] = {v0.x, v0.y, v0.z, v0.w, v1.x, v1.y, v1.z, v1.w};
  short8 pk;
#pragma unroll
  for (int j = 0; j < 8; j++) pk[j] = (short)f2bf(vals[j]);
  *(short8*)(xbf + (size_t)t * 512 + lane * 8) = pk;
  float a0 = 0.f, a1 = 0.f, a2 = 0.f, a3 = 0.f;
  const int dbase = lane * 8;
#pragma unroll
  for (int j = 0; j < 8; j++) {
    float xv = vals[j];
    a0 += xv * wsel[0][dbase + j];
    a1 += xv * wsel[1][dbase + j];
    a2 += xv * wsel[2][dbase + j];
    a3 += xv * wsel[3][dbase + j];
  }
#pragma unroll
  for (int off = 32; off >= 1; off >>= 1) {
    a0 += __shfl_down(a0, off, 64);
    a1 += __shfl_down(a1, off, 64);
    a2 += __shfl_down(a2, off, 64);
    a3 += __shfl_down(a3, off, 64);
  }
  if (lane == 0) {
    float l0 = a0 + bsel[0], l1 = a1 + bsel[1], l2 = a2 + bsel[2], l3 = a3 + bsel[3];
    float m = fmaxf(fmaxf(l0, l1), fmaxf(l2, l3));
    float e0 = __expf(l0 - m), e1 = __expf(l1 - m);
    float e2 = __expf(l2 - m), e3 = __expf(l3 - m);
    float inv = 1.0f / (e0 + e1 + e2 + e3);
    float* o = gwout + (size_t)t * 4;
    o[0] = e0 * inv; o[1] = e1 * inv; o[2] = e2 * inv; o[3] = e3 * inv;
  }
}

// ---------------- gemm4p: 4-phase double-buffered 128x128 tile ----------------
// Round-4 synthesis: the verified 4-phase counted-vmcnt skeleton (round-4
// gemm4p, BM=256) COMBINED with the 2-blocks/CU occupancy that made gemm_bt
// the fastest structure so far. 256 threads (4 waves, 2Mx2N), 64 KiB LDS
// (2 bufs x (A 128x64 + B 128x64) bf16) -> 2 blocks/CU; cross-block overlap
// hides barrier drains + epilogue while counted vmcnt keeps loads in flight.
//   P0: ds_read ALL buf0 frags (16x b128) | BAR | lgkm0 | MFMA ks=0 | BAR
//   P1: stage next buf0 tile (8 loads)          | MFMA ks=1 | vmcnt(8) | BAR
//   P2/P3: same for buf1.
// FIFO (8 loads/thread/tile, 2 tiles in flight): VMW(8) = oldest tile landed.
// Hazards: stage into buf only in the phase after its LDALL's trailing
// barrier (reads drained by LGKM0 before MFMA, ordered by BAR). No XCD
// swizzle: by-stride of lin id is gridDim.x=128 = 0 mod 8, so A-sharing
// blocks land on one XCD L2 naturally (round-2 lesson).

#define CFENCE asm volatile("" ::: "memory")
#define BAR    do { CFENCE; __builtin_amdgcn_s_barrier(); CFENCE; } while (0)
#define LGKM0  do { asm volatile("s_waitcnt lgkmcnt(0)" ::: "memory"); \
                    __builtin_amdgcn_sched_barrier(0); } while (0)
#define SCHEDB __builtin_amdgcn_sched_barrier(0)
#define VMW(n) asm volatile("s_waitcnt vmcnt(" #n ")" ::: "memory")

#define LDALL(abuf, bbuf)                                                   \
  do {                                                                      \
    _Pragma("unroll")                                                       \
    for (int i_ = 0; i_ < 4; i_++)                                          \
      _Pragma("unroll")                                                     \
      for (int ks_ = 0; ks_ < 2; ks_++)                                     \
        aF[i_][ks_] = *(const short8*)((abuf) +                             \
            (size_t)(wm + i_ * 16 + fr) * 64 +                              \
            (((ks_ * 4 + quad) ^ swz) << 3));                               \
    _Pragma("unroll")                                                       \
    for (int j_ = 0; j_ < 4; j_++)                                          \
      _Pragma("unroll")                                                     \
      for (int ks_ = 0; ks_ < 2; ks_++)                                     \
        bF[j_][ks_] = *(const short8*)((bbuf) +                             \
            (size_t)(wn + j_ * 16 + fr) * 64 +                              \
            (((ks_ * 4 + quad) ^ swz) << 3));                               \
  } while (0)

#define MMH(ks)                                                             \
  do {                                                                      \
    __builtin_amdgcn_s_setprio(1);                                          \
    _Pragma("unroll")                                                       \
    for (int i_ = 0; i_ < 4; i_++)                                          \
      _Pragma("unroll")                                                     \
      for (int j_ = 0; j_ < 4; j_++)                                        \
        acc[i_][j_] = __builtin_amdgcn_mfma_f32_16x16x32_bf16(              \
            aF[i_][ks], bF[j_][ks], acc[i_][j_], 0, 0, 0);                  \
    __builtin_amdgcn_s_setprio(0);                                          \
  } while (0)

template <int EPI>
__global__ __launch_bounds__(256, 2)
void gemm4p(const unsigned short* __restrict__ A,
            const unsigned short* __restrict__ Bt,
            void* __restrict__ C, int K, int lda, int ldb, int ldc,
            const float* __restrict__ gw,
            const float* __restrict__ bias, int colOff, int accum) {
  __shared__ unsigned short lds[4 * 128 * 64];
  const int tid = threadIdx.x;
  const int wave = tid >> 6, lane = tid & 63;
  const int lrow = lane >> 3, lslot = lane & 7, gch = lslot ^ lrow;
  const int fr = lane & 15, quad = lane >> 4, swz = fr & 7;
  const int wm = (wave >> 1) * 64, wn = (wave & 1) * 64;
  const int rowA0 = blockIdx.x * 128;
  const int rowB0 = blockIdx.y * 128;

  unsigned short* const A0 = lds;
  unsigned short* const B0 = lds + 128 * 64;
  unsigned short* const A1 = lds + 2 * 128 * 64;
  unsigned short* const B1 = lds + 3 * 128 * 64;

  // stage one full tile (A 128x64 + B 128x64) into a buffer: 8 loads/thread
  auto stT = [&](unsigned short* ab, unsigned short* bb, int kt) {
#pragma unroll
    for (int c = 0; c < 4; c++) {
      int r = wave * 32 + c * 8 + lrow;
      const unsigned short* gp = A + (size_t)(rowA0 + r) * lda + kt + gch * 8;
      __builtin_amdgcn_global_load_lds(AS1U32(gp), AS3U32(ab + (wave * 32 + c * 8) * 64), 16, 0, 0);
    }
#pragma unroll
    for (int c = 0; c < 4; c++) {
      int r = wave * 32 + c * 8 + lrow;
      const unsigned short* gp = Bt + (size_t)(rowB0 + r) * ldb + kt + gch * 8;
      __builtin_amdgcn_global_load_lds(AS1U32(gp), AS3U32(bb + (wave * 32 + c * 8) * 64), 16, 0, 0);
    }
  };

  f32x4 acc[4][4];
#pragma unroll
  for (int i = 0; i < 4; i++)
#pragma unroll
    for (int j = 0; j < 4; j++) acc[i][j] = (f32x4){0.f, 0.f, 0.f, 0.f};

  short8 aF[4][2];
  short8 bF[4][2];

  // ---- prologue: tile0 -> buf0, tile1 -> buf1 ----
  stT(A0, B0, 0);
  stT(A1, B1, 64);
  VMW(8);            // oldest 8 = tile0 landed (tile1 may be in flight)
  BAR;

  const int niter = K >> 7;   // two 64-K tiles per iteration
  for (int i = 0; i < niter - 1; i++) {
    const int kt = i * 128;
    // P0: read all buf0 fragments, compute ks=0
    LDALL(A0, B0);
    BAR; LGKM0; MMH(0); BAR;
    // P1: stage next buf0 tile, compute ks=1
    stT(A0, B0, kt + 128); SCHEDB;
    MMH(1); VMW(8); BAR;       // buf1's current tile landed
    // P2: read all buf1 fragments, compute ks=0
    LDALL(A1, B1);
    BAR; LGKM0; MMH(0); BAR;
    // P3: stage next buf1 tile, compute ks=1
    stT(A1, B1, kt + 192); SCHEDB;
    MMH(1); VMW(8); BAR;       // buf0's next tile landed
  }
  // ---- peeled last iteration (no staging) ----
  LDALL(A0, B0);
  BAR; LGKM0; MMH(0); BAR;
  MMH(1); VMW(0); BAR;
  LDALL(A1, B1);
  BAR; LGKM0; MMH(0); BAR;
  MMH(1);

  // ---- epilogue ----
  if (EPI == 1) {
    unsigned short* Cb = (unsigned short*)C;
    const int kexp = (colOff + rowB0) >> 11;
#pragma unroll
    for (int i = 0; i < 4; i++) {
#pragma unroll
      for (int reg = 0; reg < 4; reg++) {
        int r = rowA0 + wm + i * 16 + quad * 4 + reg;
        float g = gw[(size_t)r * 4 + kexp];
#pragma unroll
        for (int j = 0; j < 4; j++) {
          int n = rowB0 + wn + j * 16 + fr;
          float v = acc[i][j][reg] + bias[colOff + n];
          Cb[(size_t)r * ldc + n] = f2bf(gelu_fast(v) * g);
        }
      }
    }
  } else {
    float* Cf = (float*)C;
#pragma unroll
    for (int i = 0; i < 4; i++) {
#pragma unroll
      for (int reg = 0; reg < 4; reg++) {
        int r = rowA0 + wm + i * 16 + quad * 4 + reg;
        size_t t4 = (size_t)r * 4;
        float g0 = gw[t4], g1 = gw[t4 + 1], g2 = gw[t4 + 2], g3 = gw[t4 + 3];
#pragma unroll
        for (int j = 0; j < 4; j++) {
          int n = rowB0 + wn + j * 16 + fr;
          size_t ci = (size_t)r * 512 + n;
          float v = acc[i][j][reg];
          if (accum) v += Cf[ci];
          else v += g0 * bias[n] + g1 * bias[512 + n] +
                    g2 * bias[1024 + n] + g3 * bias[1536 + n];
          Cf[ci] = v;
        }
      }
    }
  }
}

#undef LDALL
#undef MMH

// ---------------- launch ----------------

extern "C" void kernel_launch(void* const* d_in, const int* in_sizes, int n_in,
                              void* d_out, int out_size, void* d_ws, size_t ws_size,
                              hipStream_t stream) {
  (void)in_sizes; (void)n_in; (void)out_size;
  const float* x      = (const float*)d_in[0];
  const float* gate_w = (const float*)d_in[1];
  const float* gate_b = (const float*)d_in[2];
  const float* w1     = (const float*)d_in[3];
  const float* b1     = (const float*)d_in[4];
  const float* w2     = (const float*)d_in[5];
  const float* b2     = (const float*)d_in[6];

  char* ws = (char*)d_ws;
  int*            idx   = (int*)(ws + 0);                //  16 B
  float*          gw    = (float*)(ws + 4096);           // 256 KB  [T,4]
  float*          b1cat = (float*)(ws + 266240);         //  32 KB
  float*          b2sel = (float*)(ws + 299008);         //   8 KB
  float*          kpart = (float*)(ws + 307200);         // 512 KB  [256,512]
  unsigned short* xbf   = (unsigned short*)(ws + 831488);      // 16.8 MB [T,512]
  unsigned short* w1t   = (unsigned short*)(ws + 17608704);    //  8.4 MB [8192,512]
  unsigned short* w2t   = (unsigned short*)(ws + 25997312);    //  8.4 MB [512,8192]
  unsigned short* hbuf  = (unsigned short*)(ws + 34385920);    // h' slab
  const size_t HBUF_OFF = 34385920;

  size_t avail = ws_size > HBUF_OFF ? ws_size - HBUF_OFF : 0;
  int nslab = 1;
  while (nslab < 16 && (size_t)16384 * (8192 / nslab) * 2 > avail) nslab <<= 1;
  const int slabDF = 8192 / nslab;

  reduce_part<<<256, 512, 0, stream>>>(x, kpart);
  gate_all<<<1, 1024, 0, stream>>>(kpart, gate_w, gate_b, b1, b2, idx, b1cat, b2sel);
  transpose_all<<<dim3(8, 32, 8), 256, 0, stream>>>(w1, w2, w1t, w2t, idx);
  gate_softmax_xconv<<<4096, 256, 0, stream>>>(x, gate_w, gate_b, idx, gw, xbf);

  for (int s = 0; s < nslab; s++) {
    const int c0 = s * slabDF;
    // gemm1 (K=512, gelu epilogue): 128^2 4-phase, 2 blocks/CU.
    gemm4p<1><<<dim3(128, slabDF / 128), 256, 0, stream>>>(
        xbf, w1t + (size_t)c0 * 512, hbuf,
        /*K=*/512, /*lda=*/512, /*ldb=*/512, /*ldc=*/slabDF,
        gw, b1cat, c0, 0);
    // gemm2 (long K=slabDF): 128^2 4-phase, grid 512 = 2 blocks/CU.
    gemm4p<2><<<dim3(128, 4), 256, 0, stream>>>(
        hbuf, w2t + c0, (float*)d_out,
        /*K=*/slabDF, /*lda=*/slabDF, /*ldb=*/8192, /*ldc=*/512,
        gw, b2sel, 0, s > 0);
  }
}